// Round 1
// baseline (2138.432 us; speedup 1.0000x reference)
//
#include <hip/hip_runtime.h>
#include <hip/hip_bf16.h>

#define Cc 64
#define Hc 128
#define Wc 128
#define HWc (Hc * Wc)
#define Bc 4

// ---------------------------------------------------------------------------
// conv3x3: one thread per output pixel; block = 256 threads = 2 rows x 128 w.
// grid = (H/2, Cout, B). Input tile (4 rows x 130 cols) staged in LDS per ci.
// ---------------------------------------------------------------------------
template <bool RELU_IN, bool RELU_OUT, bool MUL>
__global__ __launch_bounds__(256) void conv3x3_k(
    const float* __restrict__ in, const float* __restrict__ wgt,
    const float* __restrict__ bias, const float* __restrict__ mul,
    float* __restrict__ out)
{
    __shared__ float s_w[Cc * 9];
    __shared__ float s_in[4][132];   // +pad cols for alignment

    const int tid  = threadIdx.x;
    const int co   = blockIdx.y;
    const int b    = blockIdx.z;
    const int h0   = blockIdx.x * 2;
    const int w    = tid & 127;
    const int hoff = tid >> 7;
    const int h    = h0 + hoff;

    for (int i = tid; i < Cc * 9; i += 256) s_w[i] = wgt[co * Cc * 9 + i];

    const float* inb = in + (size_t)b * Cc * HWc;
    float acc = 0.f;

    for (int ci = 0; ci < Cc; ++ci) {
        __syncthreads();
        const float* inc = inb + ci * HWc;
        for (int i = tid; i < 4 * 130; i += 256) {
            int r  = i / 130;
            int cc = i - r * 130;
            int gh = h0 - 1 + r;
            int gw = cc - 1;
            float v = 0.f;
            if (gh >= 0 && gh < Hc && gw >= 0 && gw < Wc) {
                v = inc[gh * Wc + gw];
                if (RELU_IN) v = fmaxf(v, 0.f);
            }
            s_in[r][cc] = v;
        }
        __syncthreads();
        const float* wr = &s_w[ci * 9];
#pragma unroll
        for (int ky = 0; ky < 3; ++ky)
#pragma unroll
            for (int kx = 0; kx < 3; ++kx)
                acc = fmaf(s_in[hoff + ky][w + kx], wr[ky * 3 + kx], acc);
    }

    acc += bias[co];
    if (RELU_OUT) acc = fmaxf(acc, 0.f);
    size_t oidx = ((size_t)b * Cc + co) * HWc + (size_t)h * Wc + w;
    if (MUL) acc *= mul[oidx];
    out[oidx] = acc;
}

// ---------------------------------------------------------------------------
// conv1x1 (64->64) + ReLU. grid = (HW/256, Cout, B)
// ---------------------------------------------------------------------------
__global__ __launch_bounds__(256) void conv1x1_relu_k(
    const float* __restrict__ in, const float* __restrict__ wgt,
    const float* __restrict__ bias, float* __restrict__ out)
{
    __shared__ float s_w[Cc];
    const int tid = threadIdx.x;
    const int co  = blockIdx.y;
    const int b   = blockIdx.z;
    if (tid < Cc) s_w[tid] = wgt[co * Cc + tid];
    __syncthreads();

    const int p = blockIdx.x * 256 + tid;
    const float* inb = in + (size_t)b * Cc * HWc + p;
    float acc = bias[co];
#pragma unroll 8
    for (int ci = 0; ci < Cc; ++ci)
        acc = fmaf(inb[(size_t)ci * HWc], s_w[ci], acc);
    out[((size_t)b * Cc + co) * HWc + p] = fmaxf(acc, 0.f);
}

// ---------------------------------------------------------------------------
// conv1x1 (64->49) + kernel_normalize fused. One thread per pixel holds all
// 49 accumulators. grid = (HW/256, B)
// ---------------------------------------------------------------------------
__global__ __launch_bounds__(256) void conv1x1_lp_k(
    const float* __restrict__ in, const float* __restrict__ wgt,
    const float* __restrict__ bias, float* __restrict__ out)
{
    __shared__ float s_w[49 * Cc];
    __shared__ float s_b[49];
    const int tid = threadIdx.x;
    const int b   = blockIdx.y;
    for (int i = tid; i < 49 * Cc; i += 256) s_w[i] = wgt[i];
    if (tid < 49) s_b[tid] = bias[tid];
    __syncthreads();

    const int p = blockIdx.x * 256 + tid;
    const float* inb = in + (size_t)b * Cc * HWc + p;

    float acc[49];
#pragma unroll
    for (int k = 0; k < 49; ++k) acc[k] = s_b[k];

    for (int ci = 0; ci < Cc; ++ci) {
        float v = inb[(size_t)ci * HWc];
#pragma unroll
        for (int k = 0; k < 49; ++k)
            acc[k] = fmaf(v, s_w[k * Cc + ci], acc[k]);
    }

    float s = 0.f;
#pragma unroll
    for (int k = 0; k < 49; ++k) s += acc[k];
    const float m = s * (1.f / 49.f) - (1.f / 49.f);   // mean - 1/49

    float* ob = out + (size_t)b * 49 * HWc + p;
#pragma unroll
    for (int k = 0; k < 49; ++k) ob[(size_t)k * HWc] = acc[k] - m;
}

// ---------------------------------------------------------------------------
// Dynamic local 7x7 conv + residual. grid = (H/2, C, B), block 256 = 2x128.
// out[b,c,h,w] = x[b,c,h,w] + sum_{dy,dx} feat[b,c,h+dy-3,w+dx-3]*lp[b,dy*7+dx,h,w]
// ---------------------------------------------------------------------------
__global__ __launch_bounds__(256) void local_conv_k(
    const float* __restrict__ x, const float* __restrict__ feat,
    const float* __restrict__ lp, float* __restrict__ out)
{
    const int tid  = threadIdx.x;
    const int w    = tid & 127;
    const int hoff = tid >> 7;
    const int h    = blockIdx.x * 2 + hoff;
    const int c    = blockIdx.y;
    const int b    = blockIdx.z;

    const float* lpb = lp + (size_t)b * 49 * HWc + (size_t)h * Wc + w;
    const float* fb  = feat + ((size_t)b * Cc + c) * HWc;

    float acc = 0.f;
#pragma unroll
    for (int dy = 0; dy < 7; ++dy) {
        const int gh = h + dy - 3;
        if (gh < 0 || gh >= Hc) continue;
#pragma unroll
        for (int dx = 0; dx < 7; ++dx) {
            const int gw = w + dx - 3;
            if (gw < 0 || gw >= Wc) continue;
            acc = fmaf(fb[(size_t)gh * Wc + gw], lpb[(size_t)(dy * 7 + dx) * HWc], acc);
        }
    }

    const size_t idx = ((size_t)b * Cc + c) * HWc + (size_t)h * Wc + w;
    out[idx] = x[idx] + acc;
}

// ---------------------------------------------------------------------------
extern "C" void kernel_launch(void* const* d_in, const int* in_sizes, int n_in,
                              void* d_out, int out_size, void* d_ws, size_t ws_size,
                              hipStream_t stream)
{
    const float* x   = (const float*)d_in[0];
    const float* kf  = (const float*)d_in[1];
    const float* fw1 = (const float*)d_in[2];
    const float* fb1 = (const float*)d_in[3];
    const float* fw2 = (const float*)d_in[4];
    const float* fb2 = (const float*)d_in[5];
    const float* mw1 = (const float*)d_in[6];
    const float* mb1 = (const float*)d_in[7];
    const float* mw2 = (const float*)d_in[8];
    const float* mb2 = (const float*)d_in[9];
    const float* lw1 = (const float*)d_in[10];
    const float* lb1 = (const float*)d_in[11];
    const float* lw2 = (const float*)d_in[12];
    const float* lb2 = (const float*)d_in[13];

    float* out = (float*)d_out;
    char*  ws  = (char*)d_ws;

    const size_t NB = (size_t)Bc * Cc * HWc * sizeof(float);   // 16.8 MB
    float* bufA = (float*)ws;                 // scratch (t1 / t2 / t3)
    float* feat = (float*)(ws + NB);          // fp * mp
    float* lpb  = (float*)(ws + 2 * NB);      // 49-tap filters (12.8 MB)
    float* fp   = out;                        // park fp in d_out, overwritten at end

    dim3 blk(256);
    dim3 g3(Hc / 2, Cc, Bc);
    dim3 g1(HWc / 256, Cc, Bc);
    dim3 g2(HWc / 256, Bc);

    // feature path: relu -> conv -> relu -> conv
    conv3x3_k<true,  true,  false><<<g3, blk, 0, stream>>>(x,    fw1, fb1, nullptr, bufA);
    conv3x3_k<false, false, false><<<g3, blk, 0, stream>>>(bufA, fw2, fb2, nullptr, fp);
    // multiplicative path: conv -> relu -> conv, fused * fp
    conv3x3_k<false, true,  false><<<g3, blk, 0, stream>>>(kf,   mw1, mb1, nullptr, bufA);
    conv3x3_k<false, false, true ><<<g3, blk, 0, stream>>>(bufA, mw2, mb2, fp,      feat);
    // local filter path
    conv1x1_relu_k<<<g1, blk, 0, stream>>>(kf, lw1, lb1, bufA);
    conv1x1_lp_k <<<g2, blk, 0, stream>>>(bufA, lw2, lb2, lpb);
    // dynamic local conv + residual
    local_conv_k <<<g3, blk, 0, stream>>>(x, feat, lpb, out);
}

// Round 2
// 665.278 us; speedup vs baseline: 3.2143x; 3.2143x over previous
//
#include <hip/hip_runtime.h>
#include <hip/hip_bf16.h>

#define Cc 64
#define Hc 128
#define Wc 128
#define HWc (Hc * Wc)
#define Bc 4

// ---------------------------------------------------------------------------
// conv3x3 v2: register-tiled. Block 256 threads = 32 w-groups x 8 rows.
// Each thread: 4 horizontal pixels x 8 output channels = 32 accumulators.
// grid = (H/8, Cout/8, B). Input tile (10 x 130) staged in LDS per ci with
// register prefetch of ci+1; weights read via block-uniform scalar loads.
// ---------------------------------------------------------------------------
template <bool RELU_IN, bool RELU_OUT, bool MUL>
__global__ __launch_bounds__(256, 2) void conv3x3_v2(
    const float* __restrict__ in, const float* __restrict__ wgt,
    const float* __restrict__ bias, const float* __restrict__ mul,
    float* __restrict__ out)
{
    __shared__ float s_in[10 * 132];

    const int tid  = threadIdx.x;
    const int w4   = (tid & 31) * 4;
    const int hoff = tid >> 5;          // 0..7
    const int h0   = blockIdx.x * 8;
    const int co0  = blockIdx.y * 8;
    const int b    = blockIdx.z;

    const float* inb = in + (size_t)b * Cc * HWc;

    // Staging slot geometry (invariant over ci): 10 rows x 130 cols.
    int  goff[6];
    int  soff[6];
    bool vld[6];
#pragma unroll
    for (int s = 0; s < 6; ++s) {
        int i = tid + s * 256;
        int r = i / 130;
        int c = i - r * 130;
        int gh = h0 - 1 + r;
        int gw = c - 1;
        bool ok = (i < 1300) && gh >= 0 && gh < Hc && gw >= 0 && gw < Wc;
        vld[s]  = ok;
        goff[s] = ok ? (gh * Wc + gw) : 0;
        soff[s] = (i < 1300) ? (r * 132 + c) : -1;
    }

    float pf[6];
    {   // prefetch ci = 0
        const float* inc = inb;
#pragma unroll
        for (int s = 0; s < 6; ++s) {
            float v = vld[s] ? inc[goff[s]] : 0.f;
            if (RELU_IN) v = fmaxf(v, 0.f);
            pf[s] = v;
        }
    }
#pragma unroll
    for (int s = 0; s < 6; ++s) if (soff[s] >= 0) s_in[soff[s]] = pf[s];
    __syncthreads();

    float acc[8][4];
#pragma unroll
    for (int co = 0; co < 8; ++co)
#pragma unroll
        for (int p = 0; p < 4; ++p) acc[co][p] = 0.f;

    for (int ci = 0; ci < Cc; ++ci) {
        // prefetch next ci into registers (overlaps with compute below)
        if (ci + 1 < Cc) {
            const float* inc = inb + (size_t)(ci + 1) * HWc;
#pragma unroll
            for (int s = 0; s < 6; ++s) {
                float v = vld[s] ? inc[goff[s]] : 0.f;
                if (RELU_IN) v = fmaxf(v, 0.f);
                pf[s] = v;
            }
        }

        // load 3 input rows x 6 cols from LDS (float4 + float2, aligned)
        float iv[3][6];
#pragma unroll
        for (int ky = 0; ky < 3; ++ky) {
            const float* rp = &s_in[(hoff + ky) * 132 + w4];
            float4 a  = *(const float4*)rp;
            float2 c2 = *(const float2*)(rp + 4);
            iv[ky][0] = a.x;  iv[ky][1] = a.y;  iv[ky][2] = a.z;
            iv[ky][3] = a.w;  iv[ky][4] = c2.x; iv[ky][5] = c2.y;
        }

        const float* wp = wgt + ((size_t)co0 * Cc + ci) * 9;
#pragma unroll
        for (int co = 0; co < 8; ++co) {
            const float* wc = wp + (size_t)co * Cc * 9;   // block-uniform -> s_load
            float wv[9];
#pragma unroll
            for (int t = 0; t < 9; ++t) wv[t] = wc[t];
#pragma unroll
            for (int p = 0; p < 4; ++p) {
                float a = acc[co][p];
                a = fmaf(iv[0][p + 0], wv[0], a);
                a = fmaf(iv[0][p + 1], wv[1], a);
                a = fmaf(iv[0][p + 2], wv[2], a);
                a = fmaf(iv[1][p + 0], wv[3], a);
                a = fmaf(iv[1][p + 1], wv[4], a);
                a = fmaf(iv[1][p + 2], wv[5], a);
                a = fmaf(iv[2][p + 0], wv[6], a);
                a = fmaf(iv[2][p + 1], wv[7], a);
                a = fmaf(iv[2][p + 2], wv[8], a);
                acc[co][p] = a;
            }
        }

        __syncthreads();
        if (ci + 1 < Cc) {
#pragma unroll
            for (int s = 0; s < 6; ++s) if (soff[s] >= 0) s_in[soff[s]] = pf[s];
        }
        __syncthreads();
    }

    const int h = h0 + hoff;
#pragma unroll
    for (int co = 0; co < 8; ++co) {
        float  bv   = bias[co0 + co];
        size_t oidx = ((size_t)b * Cc + co0 + co) * HWc + (size_t)h * Wc + w4;
        float4 r;
        float* rr = (float*)&r;
#pragma unroll
        for (int p = 0; p < 4; ++p) {
            float v = acc[co][p] + bv;
            if (RELU_OUT) v = fmaxf(v, 0.f);
            rr[p] = v;
        }
        if (MUL) {
            float4 m = *(const float4*)&mul[oidx];
            r.x *= m.x; r.y *= m.y; r.z *= m.z; r.w *= m.w;
        }
        *(float4*)&out[oidx] = r;
    }
}

// ---------------------------------------------------------------------------
// conv1x1 (64->64) + ReLU. grid = (HW/256, Cout, B)
// ---------------------------------------------------------------------------
__global__ __launch_bounds__(256) void conv1x1_relu_k(
    const float* __restrict__ in, const float* __restrict__ wgt,
    const float* __restrict__ bias, float* __restrict__ out)
{
    __shared__ float s_w[Cc];
    const int tid = threadIdx.x;
    const int co  = blockIdx.y;
    const int b   = blockIdx.z;
    if (tid < Cc) s_w[tid] = wgt[co * Cc + tid];
    __syncthreads();

    const int p = blockIdx.x * 256 + tid;
    const float* inb = in + (size_t)b * Cc * HWc + p;
    float acc = bias[co];
#pragma unroll 8
    for (int ci = 0; ci < Cc; ++ci)
        acc = fmaf(inb[(size_t)ci * HWc], s_w[ci], acc);
    out[((size_t)b * Cc + co) * HWc + p] = fmaxf(acc, 0.f);
}

// ---------------------------------------------------------------------------
// conv1x1 (64->49) + kernel_normalize fused. One thread per pixel holds all
// 49 accumulators. grid = (HW/256, B)
// ---------------------------------------------------------------------------
__global__ __launch_bounds__(256) void conv1x1_lp_k(
    const float* __restrict__ in, const float* __restrict__ wgt,
    const float* __restrict__ bias, float* __restrict__ out)
{
    __shared__ float s_w[49 * Cc];
    __shared__ float s_b[49];
    const int tid = threadIdx.x;
    const int b   = blockIdx.y;
    for (int i = tid; i < 49 * Cc; i += 256) s_w[i] = wgt[i];
    if (tid < 49) s_b[tid] = bias[tid];
    __syncthreads();

    const int p = blockIdx.x * 256 + tid;
    const float* inb = in + (size_t)b * Cc * HWc + p;

    float acc[49];
#pragma unroll
    for (int k = 0; k < 49; ++k) acc[k] = s_b[k];

    for (int ci = 0; ci < Cc; ++ci) {
        float v = inb[(size_t)ci * HWc];
#pragma unroll
        for (int k = 0; k < 49; ++k)
            acc[k] = fmaf(v, s_w[k * Cc + ci], acc[k]);
    }

    float s = 0.f;
#pragma unroll
    for (int k = 0; k < 49; ++k) s += acc[k];
    const float m = s * (1.f / 49.f) - (1.f / 49.f);   // mean - 1/49

    float* ob = out + (size_t)b * 49 * HWc + p;
#pragma unroll
    for (int k = 0; k < 49; ++k) ob[(size_t)k * HWc] = acc[k] - m;
}

// ---------------------------------------------------------------------------
// Dynamic local 7x7 conv + residual. grid = (H/2, C, B), block 256 = 2x128.
// ---------------------------------------------------------------------------
__global__ __launch_bounds__(256) void local_conv_k(
    const float* __restrict__ x, const float* __restrict__ feat,
    const float* __restrict__ lp, float* __restrict__ out)
{
    const int tid  = threadIdx.x;
    const int w    = tid & 127;
    const int hoff = tid >> 7;
    const int h    = blockIdx.x * 2 + hoff;
    const int c    = blockIdx.y;
    const int b    = blockIdx.z;

    const float* lpb = lp + (size_t)b * 49 * HWc + (size_t)h * Wc + w;
    const float* fb  = feat + ((size_t)b * Cc + c) * HWc;

    float acc = 0.f;
#pragma unroll
    for (int dy = 0; dy < 7; ++dy) {
        const int gh = h + dy - 3;
        if (gh < 0 || gh >= Hc) continue;
#pragma unroll
        for (int dx = 0; dx < 7; ++dx) {
            const int gw = w + dx - 3;
            if (gw < 0 || gw >= Wc) continue;
            acc = fmaf(fb[(size_t)gh * Wc + gw], lpb[(size_t)(dy * 7 + dx) * HWc], acc);
        }
    }

    const size_t idx = ((size_t)b * Cc + c) * HWc + (size_t)h * Wc + w;
    out[idx] = x[idx] + acc;
}

// ---------------------------------------------------------------------------
extern "C" void kernel_launch(void* const* d_in, const int* in_sizes, int n_in,
                              void* d_out, int out_size, void* d_ws, size_t ws_size,
                              hipStream_t stream)
{
    const float* x   = (const float*)d_in[0];
    const float* kf  = (const float*)d_in[1];
    const float* fw1 = (const float*)d_in[2];
    const float* fb1 = (const float*)d_in[3];
    const float* fw2 = (const float*)d_in[4];
    const float* fb2 = (const float*)d_in[5];
    const float* mw1 = (const float*)d_in[6];
    const float* mb1 = (const float*)d_in[7];
    const float* mw2 = (const float*)d_in[8];
    const float* mb2 = (const float*)d_in[9];
    const float* lw1 = (const float*)d_in[10];
    const float* lb1 = (const float*)d_in[11];
    const float* lw2 = (const float*)d_in[12];
    const float* lb2 = (const float*)d_in[13];

    float* out = (float*)d_out;
    char*  ws  = (char*)d_ws;

    const size_t NB = (size_t)Bc * Cc * HWc * sizeof(float);   // 16.8 MB
    float* bufA = (float*)ws;                 // scratch
    float* feat = (float*)(ws + NB);          // fp * mp
    float* lpb  = (float*)(ws + 2 * NB);      // 49-tap filters (12.8 MB)
    float* fp   = out;                        // park fp in d_out

    dim3 blk(256);
    dim3 g3(Hc / 8, Cc / 8, Bc);
    dim3 gl(Hc / 2, Cc, Bc);
    dim3 g1(HWc / 256, Cc, Bc);
    dim3 g2(HWc / 256, Bc);

    // feature path: relu -> conv -> relu -> conv
    conv3x3_v2<true,  true,  false><<<g3, blk, 0, stream>>>(x,    fw1, fb1, nullptr, bufA);
    conv3x3_v2<false, false, false><<<g3, blk, 0, stream>>>(bufA, fw2, fb2, nullptr, fp);
    // multiplicative path: conv -> relu -> conv, fused * fp
    conv3x3_v2<false, true,  false><<<g3, blk, 0, stream>>>(kf,   mw1, mb1, nullptr, bufA);
    conv3x3_v2<false, false, true ><<<g3, blk, 0, stream>>>(bufA, mw2, mb2, fp,      feat);
    // local filter path
    conv1x1_relu_k<<<g1, blk, 0, stream>>>(kf, lw1, lb1, bufA);
    conv1x1_lp_k <<<g2, blk, 0, stream>>>(bufA, lw2, lb2, lpb);
    // dynamic local conv + residual
    local_conv_k <<<gl, blk, 0, stream>>>(x, feat, lpb, out);
}

// Round 3
// 380.847 us; speedup vs baseline: 5.6149x; 1.7468x over previous
//
#include <hip/hip_runtime.h>
#include <hip/hip_bf16.h>

#define Cc 64
#define Hc 128
#define Wc 128
#define HWc (Hc * Wc)
#define Bc 4

typedef __attribute__((ext_vector_type(8))) short short8;
typedef __attribute__((ext_vector_type(4))) float float4v;

static __device__ __forceinline__ unsigned short f2bu(float f) {
    __hip_bfloat16 h = __float2bfloat16(f);
    return *(unsigned short*)&h;
}
static __device__ __forceinline__ float bu2f(unsigned short u) {
    unsigned int x = ((unsigned int)u) << 16;
    return __uint_as_float(x);
}

// ---------------------------------------------------------------------------
// NCHW f32 -> NHWC bf16 (optional fused ReLU). One thread per pixel.
// grid = (B*HW/256)
// ---------------------------------------------------------------------------
template <bool RELU>
__global__ __launch_bounds__(256) void cvt_nhwc_k(
    const float* __restrict__ src, unsigned short* __restrict__ dst)
{
    const int px = blockIdx.x * 256 + threadIdx.x;     // 0 .. B*HW-1
    const int b  = px >> 14;                            // HW = 16384
    const int hw = px & 16383;
    const float* s = src + (size_t)b * Cc * HWc + hw;
    unsigned short* d = dst + (size_t)px * Cc;

#pragma unroll
    for (int c8 = 0; c8 < 8; ++c8) {
        unsigned int pk[4];
#pragma unroll
        for (int jp = 0; jp < 4; ++jp) {
            float v0 = s[(size_t)(c8 * 8 + jp * 2 + 0) * HWc];
            float v1 = s[(size_t)(c8 * 8 + jp * 2 + 1) * HWc];
            if (RELU) { v0 = fmaxf(v0, 0.f); v1 = fmaxf(v1, 0.f); }
            pk[jp] = (unsigned int)f2bu(v0) | ((unsigned int)f2bu(v1) << 16);
        }
        *(uint4*)(d + c8 * 8) = make_uint4(pk[0], pk[1], pk[2], pk[3]);
    }
}

// ---------------------------------------------------------------------------
// Weight pack: OIHW f32 [64][64][3][3] -> fragment-ready bf16.
// Group g (16B = 8 bf16): g = (s*4+mt)*64 + lane; element j:
//   co = mt*16 + (lane&15);  k = s*32 + (lane>>4)*8 + j;  tap = k/64; ci = k%64
// grid = (4608/256) = 18 blocks
// ---------------------------------------------------------------------------
__global__ __launch_bounds__(256) void wprep_k(
    const float* __restrict__ w, unsigned short* __restrict__ wb)
{
    const int g = blockIdx.x * 256 + threadIdx.x;
    if (g >= 64 * 576 / 8) return;
    const int lane = g & 63;
    const int smt  = g >> 6;
    const int s    = smt >> 2;
    const int mt   = smt & 3;
    const int co   = mt * 16 + (lane & 15);
    const int kb   = s * 32 + (lane >> 4) * 8;
    unsigned int pk[4];
#pragma unroll
    for (int jp = 0; jp < 4; ++jp) {
        int k0 = kb + jp * 2, k1 = k0 + 1;
        float v0 = w[((size_t)co * Cc + (k0 & 63)) * 9 + (k0 >> 6)];
        float v1 = w[((size_t)co * Cc + (k1 & 63)) * 9 + (k1 >> 6)];
        pk[jp] = (unsigned int)f2bu(v0) | ((unsigned int)f2bu(v1) << 16);
    }
    *(uint4*)(wb + (size_t)g * 8) = make_uint4(pk[0], pk[1], pk[2], pk[3]);
}

// ---------------------------------------------------------------------------
// conv3x3 via MFMA implicit GEMM.
// Block: 256 thr = 4 waves. Tile: all 64 co x 64 px (row h, cols w0..w0+63).
// K = 576 ordered k = tap*64 + ci. B-tile (3 x 66 x 64ci bf16) staged once in
// LDS with XOR chunk swizzle; A read fragment-ready from global (L1).
// grid = (W/64, H, B)
// ---------------------------------------------------------------------------
template <bool RELU_OUT, bool MUL, bool F32_NCHW_OUT>
__global__ __launch_bounds__(256) void conv3x3_mfma(
    const unsigned short* __restrict__ in,     // NHWC bf16
    const unsigned short* __restrict__ wfrag,  // fragment-ready bf16
    const float* __restrict__ bias,
    const unsigned short* __restrict__ fp_mul, // NHWC bf16 (MUL) or null
    void* __restrict__ out)
{
    __shared__ unsigned short s_b[198 * 64];   // 25344 B

    const int tid  = threadIdx.x;
    const int lane = tid & 63;
    const int wv   = tid >> 6;
    const int w0   = blockIdx.x * 64;
    const int h    = blockIdx.y;
    const int b    = blockIdx.z;

    // ---- stage input tile: rows h-1..h+1, cols w0-1..w0+64, all 64 ci ----
    if (tid < 198) {
        const int r  = tid / 66;
        const int c  = tid - r * 66;
        const int gh = h - 1 + r;
        const int gw = w0 - 1 + c;
        const bool ok = ((unsigned)gh < (unsigned)Hc) && ((unsigned)gw < (unsigned)Wc);
        const unsigned short* src =
            in + (((size_t)b * Hc + (ok ? gh : 0)) * Wc + (ok ? gw : 0)) * Cc;
        const int sw = tid & 7;
#pragma unroll
        for (int ch = 0; ch < 8; ++ch) {
            uint4 v = ok ? *(const uint4*)(src + ch * 8) : make_uint4(0, 0, 0, 0);
            *(uint4*)&s_b[tid * 64 + ((ch ^ sw) << 3)] = v;
        }
    }
    __syncthreads();

    float4v acc[4];
#pragma unroll
    for (int mt = 0; mt < 4; ++mt) acc[mt] = (float4v){0.f, 0.f, 0.f, 0.f};

    const int n_local = wv * 16 + (lane & 15);   // pixel 0..63
    const int quad    = lane >> 4;

#pragma unroll
    for (int tap = 0; tap < 9; ++tap) {
        const int ky = tap / 3, kx = tap % 3;
        const int q  = ky * 66 + n_local + kx;
        const int qs = q & 7;
#pragma unroll
        for (int half = 0; half < 2; ++half) {
            const int ch0 = half * 4 + quad;
            short8 bfr = *(const short8*)&s_b[q * 64 + ((ch0 ^ qs) << 3)];
            const int s = tap * 2 + half;
#pragma unroll
            for (int mt = 0; mt < 4; ++mt) {
                short8 afr = *(const short8*)&wfrag[(size_t)(((s * 4 + mt) << 6) + lane) << 3];
                acc[mt] = __builtin_amdgcn_mfma_f32_16x16x32_bf16(afr, bfr, acc[mt], 0, 0, 0);
            }
        }
    }

    // ---- epilogue ----
    const size_t pix = ((size_t)b * Hc + h) * Wc + w0 + n_local;
#pragma unroll
    for (int mt = 0; mt < 4; ++mt) {
        const int co0 = mt * 16 + quad * 4;
        float4 bv = *(const float4*)&bias[co0];
        float v[4] = {acc[mt][0] + bv.x, acc[mt][1] + bv.y,
                      acc[mt][2] + bv.z, acc[mt][3] + bv.w};
        if (RELU_OUT)
#pragma unroll
            for (int r = 0; r < 4; ++r) v[r] = fmaxf(v[r], 0.f);
        if (MUL) {
            uint2 m = *(const uint2*)&fp_mul[pix * Cc + co0];
            v[0] *= __uint_as_float((m.x & 0xffffu) << 16);
            v[1] *= __uint_as_float(m.x & 0xffff0000u);
            v[2] *= __uint_as_float((m.y & 0xffffu) << 16);
            v[3] *= __uint_as_float(m.y & 0xffff0000u);
        }
        if (F32_NCHW_OUT) {
            float* op = (float*)out;
#pragma unroll
            for (int r = 0; r < 4; ++r)
                op[((size_t)b * Cc + co0 + r) * HWc + (size_t)h * Wc + w0 + n_local] = v[r];
        } else {
            unsigned short* op = (unsigned short*)out;
            ushort4 pk;
            pk.x = f2bu(v[0]); pk.y = f2bu(v[1]); pk.z = f2bu(v[2]); pk.w = f2bu(v[3]);
            *(ushort4*)&op[pix * Cc + co0] = pk;
        }
    }
}

// ---------------------------------------------------------------------------
// conv1x1 (64->64) + ReLU, f32 NCHW. grid = (HW/256, Cout, B)
// ---------------------------------------------------------------------------
__global__ __launch_bounds__(256) void conv1x1_relu_k(
    const float* __restrict__ in, const float* __restrict__ wgt,
    const float* __restrict__ bias, float* __restrict__ out)
{
    __shared__ float s_w[Cc];
    const int tid = threadIdx.x;
    const int co  = blockIdx.y;
    const int b   = blockIdx.z;
    if (tid < Cc) s_w[tid] = wgt[co * Cc + tid];
    __syncthreads();

    const int p = blockIdx.x * 256 + tid;
    const float* inb = in + (size_t)b * Cc * HWc + p;
    float acc = bias[co];
#pragma unroll 8
    for (int ci = 0; ci < Cc; ++ci)
        acc = fmaf(inb[(size_t)ci * HWc], s_w[ci], acc);
    out[((size_t)b * Cc + co) * HWc + p] = fmaxf(acc, 0.f);
}

// ---------------------------------------------------------------------------
// conv1x1 (64->49) + kernel_normalize fused. grid = (HW/256, B)
// ---------------------------------------------------------------------------
__global__ __launch_bounds__(256) void conv1x1_lp_k(
    const float* __restrict__ in, const float* __restrict__ wgt,
    const float* __restrict__ bias, float* __restrict__ out)
{
    __shared__ float s_w[49 * Cc];
    __shared__ float s_b[49];
    const int tid = threadIdx.x;
    const int b   = blockIdx.y;
    for (int i = tid; i < 49 * Cc; i += 256) s_w[i] = wgt[i];
    if (tid < 49) s_b[tid] = bias[tid];
    __syncthreads();

    const int p = blockIdx.x * 256 + tid;
    const float* inb = in + (size_t)b * Cc * HWc + p;

    float acc[49];
#pragma unroll
    for (int k = 0; k < 49; ++k) acc[k] = s_b[k];

    for (int ci = 0; ci < Cc; ++ci) {
        float v = inb[(size_t)ci * HWc];
#pragma unroll
        for (int k = 0; k < 49; ++k)
            acc[k] = fmaf(v, s_w[k * Cc + ci], acc[k]);
    }

    float s = 0.f;
#pragma unroll
    for (int k = 0; k < 49; ++k) s += acc[k];
    const float m = s * (1.f / 49.f) - (1.f / 49.f);

    float* ob = out + (size_t)b * 49 * HWc + p;
#pragma unroll
    for (int k = 0; k < 49; ++k) ob[(size_t)k * HWc] = acc[k] - m;
}

// ---------------------------------------------------------------------------
// Dynamic local 7x7 conv + residual. grid = (H/2, C, B), block 256 = 2x128.
// ---------------------------------------------------------------------------
__global__ __launch_bounds__(256) void local_conv_k(
    const float* __restrict__ x, const float* __restrict__ feat,
    const float* __restrict__ lp, float* __restrict__ out)
{
    const int tid  = threadIdx.x;
    const int w    = tid & 127;
    const int hoff = tid >> 7;
    const int h    = blockIdx.x * 2 + hoff;
    const int c    = blockIdx.y;
    const int b    = blockIdx.z;

    const float* lpb = lp + (size_t)b * 49 * HWc + (size_t)h * Wc + w;
    const float* fb  = feat + ((size_t)b * Cc + c) * HWc;

    float acc = 0.f;
#pragma unroll
    for (int dy = 0; dy < 7; ++dy) {
        const int gh = h + dy - 3;
        if (gh < 0 || gh >= Hc) continue;
#pragma unroll
        for (int dx = 0; dx < 7; ++dx) {
            const int gw = w + dx - 3;
            if (gw < 0 || gw >= Wc) continue;
            acc = fmaf(fb[(size_t)gh * Wc + gw], lpb[(size_t)(dy * 7 + dx) * HWc], acc);
        }
    }

    const size_t idx = ((size_t)b * Cc + c) * HWc + (size_t)h * Wc + w;
    out[idx] = x[idx] + acc;
}

// ---------------------------------------------------------------------------
extern "C" void kernel_launch(void* const* d_in, const int* in_sizes, int n_in,
                              void* d_out, int out_size, void* d_ws, size_t ws_size,
                              hipStream_t stream)
{
    const float* x   = (const float*)d_in[0];
    const float* kf  = (const float*)d_in[1];
    const float* fw1 = (const float*)d_in[2];
    const float* fb1 = (const float*)d_in[3];
    const float* fw2 = (const float*)d_in[4];
    const float* fb2 = (const float*)d_in[5];
    const float* mw1 = (const float*)d_in[6];
    const float* mb1 = (const float*)d_in[7];
    const float* mw2 = (const float*)d_in[8];
    const float* mb2 = (const float*)d_in[9];
    const float* lw1 = (const float*)d_in[10];
    const float* lb1 = (const float*)d_in[11];
    const float* lw2 = (const float*)d_in[12];
    const float* lb2 = (const float*)d_in[13];

    float* out = (float*)d_out;
    char*  ws  = (char*)d_ws;

    const size_t NBH = (size_t)Bc * HWc * Cc * 2;      // bf16 NHWC tensor: 8.4 MB
    const size_t NBF = (size_t)Bc * Cc * HWc * 4;      // f32 NCHW tensor: 16.8 MB
    const size_t WBS = (size_t)Cc * 576 * 2;           // packed weights: 73728 B

    unsigned short* t1   = (unsigned short*)(ws);                     // bf16 NHWC
    float*          feat = (float*)(ws + NBH);                        // f32 NCHW
    float*          lpb  = (float*)(ws + NBH + NBF);                  // f32 [B][49][HW]
    unsigned short* xb   = (unsigned short*)(ws + NBH + NBF + (size_t)Bc * 49 * HWc * 4);
    unsigned short* kfb  = (unsigned short*)((char*)xb + NBH);
    unsigned short* wb1  = (unsigned short*)((char*)kfb + NBH);
    unsigned short* wb2  = (unsigned short*)((char*)wb1 + WBS);
    unsigned short* wb3  = (unsigned short*)((char*)wb2 + WBS);
    unsigned short* wb4  = (unsigned short*)((char*)wb3 + WBS);
    float*          bufA = (float*)xb;            // aliases xb+kfb (16.8 MB), used after
    unsigned short* fp   = (unsigned short*)d_out; // park fp (bf16 NHWC) in d_out

    dim3 blk(256);
    dim3 gcvt(Bc * HWc / 256);
    dim3 gw(18);
    dim3 gm(Wc / 64, Hc, Bc);
    dim3 g1(HWc / 256, Cc, Bc);
    dim3 g2(HWc / 256, Bc);
    dim3 gl(Hc / 2, Cc, Bc);

    // layout conversions + weight packing
    cvt_nhwc_k<true ><<<gcvt, blk, 0, stream>>>(x,  xb);   // relu(x) fused
    cvt_nhwc_k<false><<<gcvt, blk, 0, stream>>>(kf, kfb);
    wprep_k<<<gw, blk, 0, stream>>>(fw1, wb1);
    wprep_k<<<gw, blk, 0, stream>>>(fw2, wb2);
    wprep_k<<<gw, blk, 0, stream>>>(mw1, wb3);
    wprep_k<<<gw, blk, 0, stream>>>(mw2, wb4);

    // feature path: (relu fused in cvt) conv -> relu -> conv
    conv3x3_mfma<true,  false, false><<<gm, blk, 0, stream>>>(xb,  wb1, fb1, nullptr, t1);
    conv3x3_mfma<false, false, false><<<gm, blk, 0, stream>>>(t1,  wb2, fb2, nullptr, fp);
    // multiplicative path: conv -> relu -> conv, fused * fp -> feat (f32 NCHW)
    conv3x3_mfma<true,  false, false><<<gm, blk, 0, stream>>>(kfb, wb3, mb1, nullptr, t1);
    conv3x3_mfma<false, true,  true ><<<gm, blk, 0, stream>>>(t1,  wb4, mb2, fp,      feat);

    // local filter path (f32 VALU)
    conv1x1_relu_k<<<g1, blk, 0, stream>>>(kf, lw1, lb1, bufA);
    conv1x1_lp_k <<<g2, blk, 0, stream>>>(bufA, lw2, lb2, lpb);

    // dynamic local conv + residual
    local_conv_k <<<gl, blk, 0, stream>>>(x, feat, lpb, out);
}

// Round 4
// 244.195 us; speedup vs baseline: 8.7571x; 1.5596x over previous
//
#include <hip/hip_runtime.h>
#include <hip/hip_bf16.h>

#define Cc 64
#define Hc 128
#define Wc 128
#define HWc (Hc * Wc)
#define Bc 4

typedef __attribute__((ext_vector_type(8))) short short8;
typedef __attribute__((ext_vector_type(4))) float float4v;

static __device__ __forceinline__ unsigned short f2bu(float f) {
    __hip_bfloat16 h = __float2bfloat16(f);
    return *(unsigned short*)&h;
}

// ---------------------------------------------------------------------------
// NCHW f32 -> NHWC bf16 (optional fused ReLU). One thread per pixel.
// ---------------------------------------------------------------------------
template <bool RELU>
__global__ __launch_bounds__(256) void cvt_nhwc_k(
    const float* __restrict__ src, unsigned short* __restrict__ dst)
{
    const int px = blockIdx.x * 256 + threadIdx.x;
    const int b  = px >> 14;
    const int hw = px & 16383;
    const float* s = src + (size_t)b * Cc * HWc + hw;
    unsigned short* d = dst + (size_t)px * Cc;

#pragma unroll
    for (int c8 = 0; c8 < 8; ++c8) {
        unsigned int pk[4];
#pragma unroll
        for (int jp = 0; jp < 4; ++jp) {
            float v0 = s[(size_t)(c8 * 8 + jp * 2 + 0) * HWc];
            float v1 = s[(size_t)(c8 * 8 + jp * 2 + 1) * HWc];
            if (RELU) { v0 = fmaxf(v0, 0.f); v1 = fmaxf(v1, 0.f); }
            pk[jp] = (unsigned int)f2bu(v0) | ((unsigned int)f2bu(v1) << 16);
        }
        *(uint4*)(d + c8 * 8) = make_uint4(pk[0], pk[1], pk[2], pk[3]);
    }
}

// ---------------------------------------------------------------------------
// Weight pack 3x3: OIHW f32 -> fragment-ready bf16 (K = tap*64 + ci).
// ---------------------------------------------------------------------------
__global__ __launch_bounds__(256) void wprep_k(
    const float* __restrict__ w, unsigned short* __restrict__ wb)
{
    const int g = blockIdx.x * 256 + threadIdx.x;
    if (g >= 64 * 576 / 8) return;
    const int lane = g & 63;
    const int smt  = g >> 6;
    const int s    = smt >> 2;
    const int mt   = smt & 3;
    const int co   = mt * 16 + (lane & 15);
    const int kb   = s * 32 + (lane >> 4) * 8;
    unsigned int pk[4];
#pragma unroll
    for (int jp = 0; jp < 4; ++jp) {
        int k0 = kb + jp * 2, k1 = k0 + 1;
        float v0 = w[((size_t)co * Cc + (k0 & 63)) * 9 + (k0 >> 6)];
        float v1 = w[((size_t)co * Cc + (k1 & 63)) * 9 + (k1 >> 6)];
        pk[jp] = (unsigned int)f2bu(v0) | ((unsigned int)f2bu(v1) << 16);
    }
    *(uint4*)(wb + (size_t)g * 8) = make_uint4(pk[0], pk[1], pk[2], pk[3]);
}

// ---------------------------------------------------------------------------
// Weight pack 1x1: [Cout][64] f32 -> fragment-ready bf16, zero-pad to m=64.
// 512 groups -> grid(2).
// ---------------------------------------------------------------------------
__global__ __launch_bounds__(256) void wpack1x1_k(
    const float* __restrict__ w, int Cout, unsigned short* __restrict__ wb)
{
    const int g = blockIdx.x * 256 + threadIdx.x;
    if (g >= 512) return;
    const int lane = g & 63;
    const int smt  = g >> 6;
    const int s    = smt >> 2;
    const int mt   = smt & 3;
    const int co   = mt * 16 + (lane & 15);
    const int kb   = s * 32 + (lane >> 4) * 8;
    unsigned int pk[4];
#pragma unroll
    for (int jp = 0; jp < 4; ++jp) {
        int k0 = kb + jp * 2, k1 = k0 + 1;
        float v0 = (co < Cout) ? w[(size_t)co * Cc + k0] : 0.f;
        float v1 = (co < Cout) ? w[(size_t)co * Cc + k1] : 0.f;
        pk[jp] = (unsigned int)f2bu(v0) | ((unsigned int)f2bu(v1) << 16);
    }
    *(uint4*)(wb + (size_t)g * 8) = make_uint4(pk[0], pk[1], pk[2], pk[3]);
}

// ---------------------------------------------------------------------------
// conv3x3 via MFMA implicit GEMM (as round 3).
// ---------------------------------------------------------------------------
template <bool RELU_OUT, bool MUL, bool F32_NCHW_OUT>
__global__ __launch_bounds__(256) void conv3x3_mfma(
    const unsigned short* __restrict__ in,
    const unsigned short* __restrict__ wfrag,
    const float* __restrict__ bias,
    const unsigned short* __restrict__ fp_mul,
    void* __restrict__ out)
{
    __shared__ unsigned short s_b[198 * 64];

    const int tid  = threadIdx.x;
    const int lane = tid & 63;
    const int wv   = tid >> 6;
    const int w0   = blockIdx.x * 64;
    const int h    = blockIdx.y;
    const int b    = blockIdx.z;

    if (tid < 198) {
        const int r  = tid / 66;
        const int c  = tid - r * 66;
        const int gh = h - 1 + r;
        const int gw = w0 - 1 + c;
        const bool ok = ((unsigned)gh < (unsigned)Hc) && ((unsigned)gw < (unsigned)Wc);
        const unsigned short* src =
            in + (((size_t)b * Hc + (ok ? gh : 0)) * Wc + (ok ? gw : 0)) * Cc;
        const int sw = tid & 7;
#pragma unroll
        for (int ch = 0; ch < 8; ++ch) {
            uint4 v = ok ? *(const uint4*)(src + ch * 8) : make_uint4(0, 0, 0, 0);
            *(uint4*)&s_b[tid * 64 + ((ch ^ sw) << 3)] = v;
        }
    }
    __syncthreads();

    float4v acc[4];
#pragma unroll
    for (int mt = 0; mt < 4; ++mt) acc[mt] = (float4v){0.f, 0.f, 0.f, 0.f};

    const int n_local = wv * 16 + (lane & 15);
    const int quad    = lane >> 4;

#pragma unroll
    for (int tap = 0; tap < 9; ++tap) {
        const int ky = tap / 3, kx = tap % 3;
        const int q  = ky * 66 + n_local + kx;
        const int qs = q & 7;
#pragma unroll
        for (int half = 0; half < 2; ++half) {
            const int ch0 = half * 4 + quad;
            short8 bfr = *(const short8*)&s_b[q * 64 + ((ch0 ^ qs) << 3)];
            const int s = tap * 2 + half;
#pragma unroll
            for (int mt = 0; mt < 4; ++mt) {
                short8 afr = *(const short8*)&wfrag[(size_t)(((s * 4 + mt) << 6) + lane) << 3];
                acc[mt] = __builtin_amdgcn_mfma_f32_16x16x32_bf16(afr, bfr, acc[mt], 0, 0, 0);
            }
        }
    }

    const size_t pix = ((size_t)b * Hc + h) * Wc + w0 + n_local;
#pragma unroll
    for (int mt = 0; mt < 4; ++mt) {
        const int co0 = mt * 16 + quad * 4;
        float4 bv = *(const float4*)&bias[co0];
        float v[4] = {acc[mt][0] + bv.x, acc[mt][1] + bv.y,
                      acc[mt][2] + bv.z, acc[mt][3] + bv.w};
        if (RELU_OUT)
#pragma unroll
            for (int r = 0; r < 4; ++r) v[r] = fmaxf(v[r], 0.f);
        if (MUL) {
            uint2 m = *(const uint2*)&fp_mul[pix * Cc + co0];
            v[0] *= __uint_as_float((m.x & 0xffffu) << 16);
            v[1] *= __uint_as_float(m.x & 0xffff0000u);
            v[2] *= __uint_as_float((m.y & 0xffffu) << 16);
            v[3] *= __uint_as_float(m.y & 0xffff0000u);
        }
        if (F32_NCHW_OUT) {
            float* op = (float*)out;
#pragma unroll
            for (int r = 0; r < 4; ++r)
                op[((size_t)b * Cc + co0 + r) * HWc + (size_t)h * Wc + w0 + n_local] = v[r];
        } else {
            unsigned short* op = (unsigned short*)out;
            ushort4 pk;
            pk.x = f2bu(v[0]); pk.y = f2bu(v[1]); pk.z = f2bu(v[2]); pk.w = f2bu(v[3]);
            *(ushort4*)&op[pix * Cc + co0] = pk;
        }
    }
}

// ---------------------------------------------------------------------------
// conv1x1 (64->64) + ReLU via MFMA, NHWC bf16 -> NHWC bf16. No LDS.
// Block 256 = 4 waves x 16 px; grid = B*HW/64.
// ---------------------------------------------------------------------------
__global__ __launch_bounds__(256) void conv1x1_relu_mfma(
    const unsigned short* __restrict__ in,
    const unsigned short* __restrict__ wfrag,
    const float* __restrict__ bias,
    unsigned short* __restrict__ out)
{
    const int tid  = threadIdx.x;
    const int lane = tid & 63;
    const int wv   = tid >> 6;
    const int quad = lane >> 4;
    const size_t pix = (size_t)blockIdx.x * 64 + wv * 16 + (lane & 15);

    float4v acc[4];
#pragma unroll
    for (int mt = 0; mt < 4; ++mt) acc[mt] = (float4v){0.f, 0.f, 0.f, 0.f};

#pragma unroll
    for (int s = 0; s < 2; ++s) {
        short8 bfr = *(const short8*)&in[pix * Cc + s * 32 + quad * 8];
#pragma unroll
        for (int mt = 0; mt < 4; ++mt) {
            short8 afr = *(const short8*)&wfrag[(size_t)(((s * 4 + mt) << 6) + lane) << 3];
            acc[mt] = __builtin_amdgcn_mfma_f32_16x16x32_bf16(afr, bfr, acc[mt], 0, 0, 0);
        }
    }

#pragma unroll
    for (int mt = 0; mt < 4; ++mt) {
        const int co0 = mt * 16 + quad * 4;
        float4 bv = *(const float4*)&bias[co0];
        ushort4 pk;
        pk.x = f2bu(fmaxf(acc[mt][0] + bv.x, 0.f));
        pk.y = f2bu(fmaxf(acc[mt][1] + bv.y, 0.f));
        pk.z = f2bu(fmaxf(acc[mt][2] + bv.z, 0.f));
        pk.w = f2bu(fmaxf(acc[mt][3] + bv.w, 0.f));
        *(ushort4*)&out[pix * Cc + co0] = pk;
    }
}

// ---------------------------------------------------------------------------
// conv1x1 (64->49, m-padded to 64) via MFMA + fused kernel_normalize.
// In NHWC bf16; out f32 plane layout [B][49][H][W]. grid = B*HW/64.
// ---------------------------------------------------------------------------
__global__ __launch_bounds__(256) void conv1x1_lp_mfma(
    const unsigned short* __restrict__ in,
    const unsigned short* __restrict__ wfrag,
    const float* __restrict__ bias,
    float* __restrict__ out)
{
    const int tid  = threadIdx.x;
    const int lane = tid & 63;
    const int wv   = tid >> 6;
    const int quad = lane >> 4;
    const size_t pix = (size_t)blockIdx.x * 64 + wv * 16 + (lane & 15);

    float4v acc[4];
#pragma unroll
    for (int mt = 0; mt < 4; ++mt) acc[mt] = (float4v){0.f, 0.f, 0.f, 0.f};

#pragma unroll
    for (int s = 0; s < 2; ++s) {
        short8 bfr = *(const short8*)&in[pix * Cc + s * 32 + quad * 8];
#pragma unroll
        for (int mt = 0; mt < 4; ++mt) {
            short8 afr = *(const short8*)&wfrag[(size_t)(((s * 4 + mt) << 6) + lane) << 3];
            acc[mt] = __builtin_amdgcn_mfma_f32_16x16x32_bf16(afr, bfr, acc[mt], 0, 0, 0);
        }
    }

    // add bias (taps < 49 only) and accumulate partial sum over this lane's taps
    float v[4][4];
    float partial = 0.f;
#pragma unroll
    for (int mt = 0; mt < 4; ++mt) {
#pragma unroll
        for (int r = 0; r < 4; ++r) {
            const int tap = mt * 16 + quad * 4 + r;
            float val = (tap < 49) ? (acc[mt][r] + bias[tap]) : 0.f;
            v[mt][r] = val;
            partial += val;
        }
    }
    // reduce over quads (rows of this pixel's column live in lanes ^16, ^32)
    partial += __shfl_xor(partial, 16, 64);
    partial += __shfl_xor(partial, 32, 64);
    const float m = partial * (1.f / 49.f) - (1.f / 49.f);

    const int b  = (int)(pix >> 14);
    const int hw = (int)(pix & 16383);
#pragma unroll
    for (int mt = 0; mt < 4; ++mt) {
#pragma unroll
        for (int r = 0; r < 4; ++r) {
            const int tap = mt * 16 + quad * 4 + r;
            if (tap < 49)
                out[((size_t)b * 49 + tap) * HWc + hw] = v[mt][r] - m;
        }
    }
}

// ---------------------------------------------------------------------------
// Dynamic local 7x7 conv + residual, v2: 4 channels x 4 pixels per thread.
// Block 256 = 32 w-groups x 8 rows. grid = (H/8, C/4, B).
// ---------------------------------------------------------------------------
__global__ __launch_bounds__(256) void local_conv_v2(
    const float* __restrict__ x, const float* __restrict__ feat,
    const float* __restrict__ lp, float* __restrict__ out)
{
    const int tid = threadIdx.x;
    const int w4  = (tid & 31) * 4;
    const int ro  = tid >> 5;
    const int h   = blockIdx.x * 8 + ro;
    const int c0  = blockIdx.y * 4;
    const int b   = blockIdx.z;

    // column-validity masks for window elements e (gw = w4-4+e); e 4..7 always valid
    float msk[12];
#pragma unroll
    for (int e = 0; e < 12; ++e) {
        int gw = w4 - 4 + e;
        msk[e] = ((unsigned)gw < (unsigned)Wc) ? 1.f : 0.f;
    }

    float acc[4][4];
#pragma unroll
    for (int ch = 0; ch < 4; ++ch)
#pragma unroll
        for (int p = 0; p < 4; ++p) acc[ch][p] = 0.f;

    const float* lpb = lp + (size_t)b * 49 * HWc + (size_t)h * Wc + w4;
    const float* fb  = feat + ((size_t)b * Cc + c0) * HWc;

#pragma unroll
    for (int dy = 0; dy < 7; ++dy) {
        const int gh = h + dy - 3;
        if ((unsigned)gh >= (unsigned)Hc) continue;

        float4 lp4[7];
#pragma unroll
        for (int dx = 0; dx < 7; ++dx)
            lp4[dx] = *(const float4*)&lpb[(size_t)(dy * 7 + dx) * HWc];

        const float* frow = fb + (size_t)gh * Wc + w4;
#pragma unroll
        for (int ch = 0; ch < 4; ++ch) {
            const float* fr = frow + (size_t)ch * HWc;
            float4 a  = *(const float4*)(fr - 4);
            float4 bq = *(const float4*)(fr);
            float4 cq = *(const float4*)(fr + 4);
            float f[12];
            f[0]  = a.x;            f[1]  = a.y * msk[1];
            f[2]  = a.z * msk[2];   f[3]  = a.w * msk[3];
            f[4]  = bq.x;           f[5]  = bq.y;
            f[6]  = bq.z;           f[7]  = bq.w;
            f[8]  = cq.x * msk[8];  f[9]  = cq.y * msk[9];
            f[10] = cq.z * msk[10]; f[11] = cq.w;
#pragma unroll
            for (int dx = 0; dx < 7; ++dx) {
                const float* lpv = (const float*)&lp4[dx];
#pragma unroll
                for (int p = 0; p < 4; ++p)
                    acc[ch][p] = fmaf(f[p + dx + 1], lpv[p], acc[ch][p]);
            }
        }
    }

#pragma unroll
    for (int ch = 0; ch < 4; ++ch) {
        const size_t idx = ((size_t)b * Cc + c0 + ch) * HWc + (size_t)h * Wc + w4;
        float4 xv = *(const float4*)&x[idx];
        float4 r  = {acc[ch][0] + xv.x, acc[ch][1] + xv.y,
                     acc[ch][2] + xv.z, acc[ch][3] + xv.w};
        *(float4*)&out[idx] = r;
    }
}

// ---------------------------------------------------------------------------
extern "C" void kernel_launch(void* const* d_in, const int* in_sizes, int n_in,
                              void* d_out, int out_size, void* d_ws, size_t ws_size,
                              hipStream_t stream)
{
    const float* x   = (const float*)d_in[0];
    const float* kf  = (const float*)d_in[1];
    const float* fw1 = (const float*)d_in[2];
    const float* fb1 = (const float*)d_in[3];
    const float* fw2 = (const float*)d_in[4];
    const float* fb2 = (const float*)d_in[5];
    const float* mw1 = (const float*)d_in[6];
    const float* mb1 = (const float*)d_in[7];
    const float* mw2 = (const float*)d_in[8];
    const float* mb2 = (const float*)d_in[9];
    const float* lw1 = (const float*)d_in[10];
    const float* lb1 = (const float*)d_in[11];
    const float* lw2 = (const float*)d_in[12];
    const float* lb2 = (const float*)d_in[13];

    float* out = (float*)d_out;
    char*  ws  = (char*)d_ws;

    const size_t NBH = (size_t)Bc * HWc * Cc * 2;   // bf16 NHWC: 8.4 MB
    const size_t NBF = (size_t)Bc * Cc * HWc * 4;   // f32 NCHW: 16.8 MB
    const size_t LPB = (size_t)Bc * 49 * HWc * 4;   // 12.8 MB
    const size_t WBS = (size_t)Cc * 576 * 2;        // 73728 B
    const size_t W1S = (size_t)512 * 8 * 2;         // 8192 B

    unsigned short* t1   = (unsigned short*)(ws);            // bf16 NHWC (also t2)
    float*          feat = (float*)(ws + NBH);
    float*          lpb  = (float*)(ws + NBH + NBF);
    unsigned short* xb   = (unsigned short*)(ws + NBH + NBF + LPB);
    unsigned short* kfb  = (unsigned short*)((char*)xb + NBH);
    unsigned short* wb1  = (unsigned short*)((char*)kfb + NBH);
    unsigned short* wb2  = (unsigned short*)((char*)wb1 + WBS);
    unsigned short* wb3  = (unsigned short*)((char*)wb2 + WBS);
    unsigned short* wb4  = (unsigned short*)((char*)wb3 + WBS);
    unsigned short* wl1  = (unsigned short*)((char*)wb4 + WBS);
    unsigned short* wl2  = (unsigned short*)((char*)wl1 + W1S);
    unsigned short* fp   = (unsigned short*)d_out;           // park fp in d_out

    dim3 blk(256);
    dim3 gcvt(Bc * HWc / 256);
    dim3 gw(18);
    dim3 gm(Wc / 64, Hc, Bc);
    dim3 gp(Bc * HWc / 64);
    dim3 glc(Hc / 8, Cc / 4, Bc);

    // layout conversions + weight packing
    cvt_nhwc_k<true ><<<gcvt, blk, 0, stream>>>(x,  xb);
    cvt_nhwc_k<false><<<gcvt, blk, 0, stream>>>(kf, kfb);
    wprep_k<<<gw, blk, 0, stream>>>(fw1, wb1);
    wprep_k<<<gw, blk, 0, stream>>>(fw2, wb2);
    wprep_k<<<gw, blk, 0, stream>>>(mw1, wb3);
    wprep_k<<<gw, blk, 0, stream>>>(mw2, wb4);
    wpack1x1_k<<<dim3(2), blk, 0, stream>>>(lw1, 64, wl1);
    wpack1x1_k<<<dim3(2), blk, 0, stream>>>(lw2, 49, wl2);

    // feature path
    conv3x3_mfma<true,  false, false><<<gm, blk, 0, stream>>>(xb,  wb1, fb1, nullptr, t1);
    conv3x3_mfma<false, false, false><<<gm, blk, 0, stream>>>(t1,  wb2, fb2, nullptr, fp);
    // multiplicative path (fused * fp -> feat f32 NCHW)
    conv3x3_mfma<true,  false, false><<<gm, blk, 0, stream>>>(kfb, wb3, mb1, nullptr, t1);
    conv3x3_mfma<false, true,  true ><<<gm, blk, 0, stream>>>(t1,  wb4, mb2, fp,      feat);

    // local filter path via MFMA (t1 free after conv #4 -> reuse as t2)
    conv1x1_relu_mfma<<<gp, blk, 0, stream>>>(kfb, wl1, lb1, t1);
    conv1x1_lp_mfma  <<<gp, blk, 0, stream>>>(t1,  wl2, lb2, lpb);

    // dynamic local conv + residual
    local_conv_v2<<<glc, blk, 0, stream>>>(x, feat, lpb, out);
}

// Round 5
// 209.545 us; speedup vs baseline: 10.2051x; 1.1654x over previous
//
#include <hip/hip_runtime.h>
#include <hip/hip_bf16.h>

#define Cc 64
#define Hc 128
#define Wc 128
#define HWc (Hc * Wc)
#define Bc 4

typedef __attribute__((ext_vector_type(8))) short short8;
typedef __attribute__((ext_vector_type(4))) float float4v;

static __device__ __forceinline__ unsigned short f2bu(float f) {
    __hip_bfloat16 h = __float2bfloat16(f);
    return *(unsigned short*)&h;
}

// ---------------------------------------------------------------------------
// Merged NCHW f32 -> NHWC bf16 for x (fused ReLU) and kf. grid = 512.
// ---------------------------------------------------------------------------
__global__ __launch_bounds__(256) void cvt_both_k(
    const float* __restrict__ x, const float* __restrict__ kf,
    unsigned short* __restrict__ xb, unsigned short* __restrict__ kfb)
{
    const int bid = blockIdx.x;
    const bool isx = bid < 256;
    const float* src = isx ? x : kf;
    unsigned short* dst = isx ? xb : kfb;
    const int px = (isx ? bid : bid - 256) * 256 + threadIdx.x;
    const int b  = px >> 14;
    const int hw = px & 16383;
    const float* s = src + (size_t)b * Cc * HWc + hw;
    unsigned short* d = dst + (size_t)px * Cc;

#pragma unroll
    for (int c8 = 0; c8 < 8; ++c8) {
        unsigned int pk[4];
#pragma unroll
        for (int jp = 0; jp < 4; ++jp) {
            float v0 = s[(size_t)(c8 * 8 + jp * 2 + 0) * HWc];
            float v1 = s[(size_t)(c8 * 8 + jp * 2 + 1) * HWc];
            if (isx) { v0 = fmaxf(v0, 0.f); v1 = fmaxf(v1, 0.f); }
            pk[jp] = (unsigned int)f2bu(v0) | ((unsigned int)f2bu(v1) << 16);
        }
        *(uint4*)(d + c8 * 8) = make_uint4(pk[0], pk[1], pk[2], pk[3]);
    }
}

// ---------------------------------------------------------------------------
// All weight packing in one launch. Blocks 0..71: four 3x3 convs (18 each);
// blocks 72..75: two 1x1 convs (2 each).
// wbase layout: wb1|wb2|wb3|wb4 (36864 shorts each) then wl1|wl2 (4096 each).
// ---------------------------------------------------------------------------
__global__ __launch_bounds__(256) void wpack_all_k(
    const float* __restrict__ fw1, const float* __restrict__ fw2,
    const float* __restrict__ mw1, const float* __restrict__ mw2,
    const float* __restrict__ lw1, const float* __restrict__ lw2,
    unsigned short* __restrict__ wbase)
{
    const int bid = blockIdx.x;
    const int tid = threadIdx.x;
    if (bid < 72) {
        const int which = bid / 18;
        const float* w = (which == 0) ? fw1 : (which == 1) ? fw2 : (which == 2) ? mw1 : mw2;
        unsigned short* wb = wbase + (size_t)which * 36864;
        const int g = (bid % 18) * 256 + tid;
        if (g >= 4608) return;
        const int lane = g & 63;
        const int smt  = g >> 6;
        const int s    = smt >> 2;
        const int mt   = smt & 3;
        const int co   = mt * 16 + (lane & 15);
        const int kb   = s * 32 + (lane >> 4) * 8;
        unsigned int pk[4];
#pragma unroll
        for (int jp = 0; jp < 4; ++jp) {
            int k0 = kb + jp * 2, k1 = k0 + 1;
            float v0 = w[((size_t)co * Cc + (k0 & 63)) * 9 + (k0 >> 6)];
            float v1 = w[((size_t)co * Cc + (k1 & 63)) * 9 + (k1 >> 6)];
            pk[jp] = (unsigned int)f2bu(v0) | ((unsigned int)f2bu(v1) << 16);
        }
        *(uint4*)(wb + (size_t)g * 8) = make_uint4(pk[0], pk[1], pk[2], pk[3]);
    } else {
        const int which = (bid - 72) >> 1;             // 0: lw1, 1: lw2
        const float* w = which ? lw2 : lw1;
        const int Cout = which ? 49 : 64;
        unsigned short* wb = wbase + 4 * 36864 + (size_t)which * 4096;
        const int g = ((bid - 72) & 1) * 256 + tid;
        const int lane = g & 63;
        const int smt  = g >> 6;
        const int s    = smt >> 2;
        const int mt   = smt & 3;
        const int co   = mt * 16 + (lane & 15);
        const int kb   = s * 32 + (lane >> 4) * 8;
        unsigned int pk[4];
#pragma unroll
        for (int jp = 0; jp < 4; ++jp) {
            int k0 = kb + jp * 2, k1 = k0 + 1;
            float v0 = (co < Cout) ? w[(size_t)co * Cc + k0] : 0.f;
            float v1 = (co < Cout) ? w[(size_t)co * Cc + k1] : 0.f;
            pk[jp] = (unsigned int)f2bu(v0) | ((unsigned int)f2bu(v1) << 16);
        }
        *(uint4*)(wb + (size_t)g * 8) = make_uint4(pk[0], pk[1], pk[2], pk[3]);
    }
}

// ---------------------------------------------------------------------------
// conv3x3 v3: 2 output rows x 64 px x 64 co per block; 4 waves in 2x2
// (row, co-half) split, each wave 32co x 64px. Input tile 4 rows x 66 px
// staged once (33792 B LDS, XOR swizzle). grid = (W/64, H/2, B).
// ---------------------------------------------------------------------------
template <bool RELU_OUT, bool MUL, bool F32_NCHW_OUT>
__global__ __launch_bounds__(256) void conv3x3_v3(
    const unsigned short* __restrict__ in,
    const unsigned short* __restrict__ wfrag,
    const float* __restrict__ bias,
    const unsigned short* __restrict__ fp_mul,
    void* __restrict__ out)
{
    __shared__ unsigned short s_b[264 * 64];   // 33792 B

    const int tid  = threadIdx.x;
    const int lane = tid & 63;
    const int wv   = tid >> 6;
    const int w0   = blockIdx.x * 64;
    const int h0   = blockIdx.y * 2;
    const int b    = blockIdx.z;

    // ---- stage 4 rows (h0-1..h0+2) x 66 cols x 64 ch ----
    for (int u = tid; u < 264; u += 256) {
        const int r  = u / 66;
        const int c  = u - r * 66;
        const int gh = h0 - 1 + r;
        const int gw = w0 - 1 + c;
        const bool ok = ((unsigned)gh < (unsigned)Hc) && ((unsigned)gw < (unsigned)Wc);
        const unsigned short* src =
            in + (((size_t)b * Hc + (ok ? gh : 0)) * Wc + (ok ? gw : 0)) * Cc;
        const int sw = u & 7;
#pragma unroll
        for (int ch = 0; ch < 8; ++ch) {
            uint4 v = ok ? *(const uint4*)(src + ch * 8) : make_uint4(0, 0, 0, 0);
            *(uint4*)&s_b[u * 64 + ((ch ^ sw) << 3)] = v;
        }
    }
    __syncthreads();

    const int rowsel = wv >> 1;      // output row within tile
    const int cohalf = wv & 1;       // which 32 output channels
    const int quad   = lane >> 4;
    const int n15    = lane & 15;

    float4v acc[2][4];
#pragma unroll
    for (int m = 0; m < 2; ++m)
#pragma unroll
        for (int nt = 0; nt < 4; ++nt) acc[m][nt] = (float4v){0.f, 0.f, 0.f, 0.f};

#pragma unroll
    for (int tap = 0; tap < 9; ++tap) {
        const int ky = tap / 3, kx = tap % 3;
#pragma unroll
        for (int half = 0; half < 2; ++half) {
            const int s   = tap * 2 + half;
            const int ch0 = half * 4 + quad;
            short8 afr[2];
#pragma unroll
            for (int m = 0; m < 2; ++m) {
                const int mt = cohalf * 2 + m;
                afr[m] = *(const short8*)&wfrag[(size_t)(((s * 4 + mt) << 6) + lane) << 3];
            }
#pragma unroll
            for (int nt = 0; nt < 4; ++nt) {
                const int q = (rowsel + ky) * 66 + nt * 16 + n15 + kx;
                short8 bfr = *(const short8*)&s_b[q * 64 + ((ch0 ^ (q & 7)) << 3)];
#pragma unroll
                for (int m = 0; m < 2; ++m)
                    acc[m][nt] = __builtin_amdgcn_mfma_f32_16x16x32_bf16(afr[m], bfr, acc[m][nt], 0, 0, 0);
            }
        }
    }

    // ---- epilogue ----
    const int h = h0 + rowsel;
#pragma unroll
    for (int m = 0; m < 2; ++m) {
        const int mt  = cohalf * 2 + m;
        const int co0 = mt * 16 + quad * 4;
        float4 bv = *(const float4*)&bias[co0];
#pragma unroll
        for (int nt = 0; nt < 4; ++nt) {
            const size_t pix = ((size_t)b * Hc + h) * Wc + w0 + nt * 16 + n15;
            float v[4] = {acc[m][nt][0] + bv.x, acc[m][nt][1] + bv.y,
                          acc[m][nt][2] + bv.z, acc[m][nt][3] + bv.w};
            if (RELU_OUT)
#pragma unroll
                for (int r = 0; r < 4; ++r) v[r] = fmaxf(v[r], 0.f);
            if (MUL) {
                uint2 mm = *(const uint2*)&fp_mul[pix * Cc + co0];
                v[0] *= __uint_as_float((mm.x & 0xffffu) << 16);
                v[1] *= __uint_as_float(mm.x & 0xffff0000u);
                v[2] *= __uint_as_float((mm.y & 0xffffu) << 16);
                v[3] *= __uint_as_float(mm.y & 0xffff0000u);
            }
            if (F32_NCHW_OUT) {
                float* op = (float*)out;
#pragma unroll
                for (int r = 0; r < 4; ++r)
                    op[((size_t)b * Cc + co0 + r) * HWc + (size_t)h * Wc + w0 + nt * 16 + n15] = v[r];
            } else {
                unsigned short* op = (unsigned short*)out;
                ushort4 pk;
                pk.x = f2bu(v[0]); pk.y = f2bu(v[1]); pk.z = f2bu(v[2]); pk.w = f2bu(v[3]);
                *(ushort4*)&op[pix * Cc + co0] = pk;
            }
        }
    }
}

// ---------------------------------------------------------------------------
// Fused local-filter path: conv1x1(64->64)+ReLU -> conv1x1(64->49)+normalize.
// Per wave: 16 px. GEMM1 C-layout relayouted via 2 KB LDS tile into GEMM2
// B-operand. grid = B*HW/64, block 256 (4 waves).
// ---------------------------------------------------------------------------
__global__ __launch_bounds__(256) void lp_fused_k(
    const unsigned short* __restrict__ in,    // kfb NHWC bf16
    const unsigned short* __restrict__ w1,    // packed lw1
    const float* __restrict__ b1,
    const unsigned short* __restrict__ w2,    // packed lw2
    const float* __restrict__ b2,
    float* __restrict__ out)                  // [B][49][HW] f32
{
    __shared__ unsigned short s_t[4 * 1024];  // 16px x 64ch per wave

    const int tid  = threadIdx.x;
    const int lane = tid & 63;
    const int wv   = tid >> 6;
    const int quad = lane >> 4;
    const int p    = lane & 15;
    const size_t pix = (size_t)blockIdx.x * 64 + wv * 16 + p;
    unsigned short* st = &s_t[wv * 1024];

    // ---- GEMM1: t2 = relu(W1 * kf + b1) ----
    float4v acc1[4];
#pragma unroll
    for (int mt = 0; mt < 4; ++mt) acc1[mt] = (float4v){0.f, 0.f, 0.f, 0.f};
#pragma unroll
    for (int s = 0; s < 2; ++s) {
        short8 bfr = *(const short8*)&in[pix * Cc + s * 32 + quad * 8];
#pragma unroll
        for (int mt = 0; mt < 4; ++mt) {
            short8 afr = *(const short8*)&w1[(size_t)(((s * 4 + mt) << 6) + lane) << 3];
            acc1[mt] = __builtin_amdgcn_mfma_f32_16x16x32_bf16(afr, bfr, acc1[mt], 0, 0, 0);
        }
    }

    // write t2 fragment to LDS (bank-swizzled), co = mt*16 + quad*4 + r
#pragma unroll
    for (int mt = 0; mt < 4; ++mt) {
        const int co0 = mt * 16 + quad * 4;
        float4 bv = *(const float4*)&b1[co0];
        ushort4 pk;
        pk.x = f2bu(fmaxf(acc1[mt][0] + bv.x, 0.f));
        pk.y = f2bu(fmaxf(acc1[mt][1] + bv.y, 0.f));
        pk.z = f2bu(fmaxf(acc1[mt][2] + bv.z, 0.f));
        pk.w = f2bu(fmaxf(acc1[mt][3] + bv.w, 0.f));
        const int cg = co0 >> 3;                       // = mt*2 + (quad>>1)
        *(ushort4*)&st[p * 64 + ((cg ^ (p & 7)) << 3) + (quad & 1) * 4] = pk;
    }
    __syncthreads();

    // ---- GEMM2: lp = W2 * t2 + b2, then normalize ----
    float4v acc2[4];
#pragma unroll
    for (int mt = 0; mt < 4; ++mt) acc2[mt] = (float4v){0.f, 0.f, 0.f, 0.f};
#pragma unroll
    for (int s = 0; s < 2; ++s) {
        const int cg = s * 4 + quad;
        short8 bfr = *(const short8*)&st[p * 64 + ((cg ^ (p & 7)) << 3)];
#pragma unroll
        for (int mt = 0; mt < 4; ++mt) {
            short8 afr = *(const short8*)&w2[(size_t)(((s * 4 + mt) << 6) + lane) << 3];
            acc2[mt] = __builtin_amdgcn_mfma_f32_16x16x32_bf16(afr, bfr, acc2[mt], 0, 0, 0);
        }
    }

    float v[4][4];
    float partial = 0.f;
#pragma unroll
    for (int mt = 0; mt < 4; ++mt) {
#pragma unroll
        for (int r = 0; r < 4; ++r) {
            const int tap = mt * 16 + quad * 4 + r;
            float val = (tap < 49) ? (acc2[mt][r] + b2[tap]) : 0.f;
            v[mt][r] = val;
            partial += val;
        }
    }
    partial += __shfl_xor(partial, 16, 64);
    partial += __shfl_xor(partial, 32, 64);
    const float m = partial * (1.f / 49.f) - (1.f / 49.f);

    const int b  = (int)(pix >> 14);
    const int hw = (int)(pix & 16383);
#pragma unroll
    for (int mt = 0; mt < 4; ++mt) {
#pragma unroll
        for (int r = 0; r < 4; ++r) {
            const int tap = mt * 16 + quad * 4 + r;
            if (tap < 49)
                out[((size_t)b * 49 + tap) * HWc + hw] = v[mt][r] - m;
        }
    }
}

// ---------------------------------------------------------------------------
// Dynamic local 7x7 conv + residual, v2 (round-4 version, unchanged).
// ---------------------------------------------------------------------------
__global__ __launch_bounds__(256) void local_conv_v2(
    const float* __restrict__ x, const float* __restrict__ feat,
    const float* __restrict__ lp, float* __restrict__ out)
{
    const int tid = threadIdx.x;
    const int w4  = (tid & 31) * 4;
    const int ro  = tid >> 5;
    const int h   = blockIdx.x * 8 + ro;
    const int c0  = blockIdx.y * 4;
    const int b   = blockIdx.z;

    float msk[12];
#pragma unroll
    for (int e = 0; e < 12; ++e) {
        int gw = w4 - 4 + e;
        msk[e] = ((unsigned)gw < (unsigned)Wc) ? 1.f : 0.f;
    }

    float acc[4][4];
#pragma unroll
    for (int ch = 0; ch < 4; ++ch)
#pragma unroll
        for (int p = 0; p < 4; ++p) acc[ch][p] = 0.f;

    const float* lpb = lp + (size_t)b * 49 * HWc + (size_t)h * Wc + w4;
    const float* fb  = feat + ((size_t)b * Cc + c0) * HWc;

#pragma unroll
    for (int dy = 0; dy < 7; ++dy) {
        const int gh = h + dy - 3;
        if ((unsigned)gh >= (unsigned)Hc) continue;

        float4 lp4[7];
#pragma unroll
        for (int dx = 0; dx < 7; ++dx)
            lp4[dx] = *(const float4*)&lpb[(size_t)(dy * 7 + dx) * HWc];

        const float* frow = fb + (size_t)gh * Wc + w4;
#pragma unroll
        for (int ch = 0; ch < 4; ++ch) {
            const float* fr = frow + (size_t)ch * HWc;
            float4 a  = *(const float4*)(fr - 4);
            float4 bq = *(const float4*)(fr);
            float4 cq = *(const float4*)(fr + 4);
            float f[12];
            f[0]  = a.x;            f[1]  = a.y * msk[1];
            f[2]  = a.z * msk[2];   f[3]  = a.w * msk[3];
            f[4]  = bq.x;           f[5]  = bq.y;
            f[6]  = bq.z;           f[7]  = bq.w;
            f[8]  = cq.x * msk[8];  f[9]  = cq.y * msk[9];
            f[10] = cq.z * msk[10]; f[11] = cq.w;
#pragma unroll
            for (int dx = 0; dx < 7; ++dx) {
                const float* lpv = (const float*)&lp4[dx];
#pragma unroll
                for (int p = 0; p < 4; ++p)
                    acc[ch][p] = fmaf(f[p + dx + 1], lpv[p], acc[ch][p]);
            }
        }
    }

#pragma unroll
    for (int ch = 0; ch < 4; ++ch) {
        const size_t idx = ((size_t)b * Cc + c0 + ch) * HWc + (size_t)h * Wc + w4;
        float4 xv = *(const float4*)&x[idx];
        float4 r  = {acc[ch][0] + xv.x, acc[ch][1] + xv.y,
                     acc[ch][2] + xv.z, acc[ch][3] + xv.w};
        *(float4*)&out[idx] = r;
    }
}

// ---------------------------------------------------------------------------
extern "C" void kernel_launch(void* const* d_in, const int* in_sizes, int n_in,
                              void* d_out, int out_size, void* d_ws, size_t ws_size,
                              hipStream_t stream)
{
    const float* x   = (const float*)d_in[0];
    const float* kf  = (const float*)d_in[1];
    const float* fw1 = (const float*)d_in[2];
    const float* fb1 = (const float*)d_in[3];
    const float* fw2 = (const float*)d_in[4];
    const float* fb2 = (const float*)d_in[5];
    const float* mw1 = (const float*)d_in[6];
    const float* mb1 = (const float*)d_in[7];
    const float* mw2 = (const float*)d_in[8];
    const float* mb2 = (const float*)d_in[9];
    const float* lw1 = (const float*)d_in[10];
    const float* lb1 = (const float*)d_in[11];
    const float* lw2 = (const float*)d_in[12];
    const float* lb2 = (const float*)d_in[13];

    float* out = (float*)d_out;
    char*  ws  = (char*)d_ws;

    const size_t NBH = (size_t)Bc * HWc * Cc * 2;   // bf16 NHWC: 8.4 MB
    const size_t NBF = (size_t)Bc * Cc * HWc * 4;   // f32 NCHW: 16.8 MB
    const size_t LPB = (size_t)Bc * 49 * HWc * 4;   // 12.8 MB

    unsigned short* t1    = (unsigned short*)(ws);
    float*          feat  = (float*)(ws + NBH);
    float*          lpb   = (float*)(ws + NBH + NBF);
    unsigned short* xb    = (unsigned short*)(ws + NBH + NBF + LPB);
    unsigned short* kfb   = (unsigned short*)((char*)xb + NBH);
    unsigned short* wbase = (unsigned short*)((char*)kfb + NBH);
    unsigned short* wb1   = wbase;
    unsigned short* wb2   = wbase + 36864;
    unsigned short* wb3   = wbase + 2 * 36864;
    unsigned short* wb4   = wbase + 3 * 36864;
    unsigned short* wl1   = wbase + 4 * 36864;
    unsigned short* wl2   = wbase + 4 * 36864 + 4096;
    unsigned short* fp    = (unsigned short*)d_out;   // park fp in d_out

    dim3 blk(256);
    dim3 gm(Wc / 64, Hc / 2, Bc);
    dim3 gp(Bc * HWc / 64);
    dim3 glc(Hc / 8, Cc / 4, Bc);

    cvt_both_k<<<dim3(512), blk, 0, stream>>>(x, kf, xb, kfb);
    wpack_all_k<<<dim3(76), blk, 0, stream>>>(fw1, fw2, mw1, mw2, lw1, lw2, wbase);

    // feature path
    conv3x3_v3<true,  false, false><<<gm, blk, 0, stream>>>(xb,  wb1, fb1, nullptr, t1);
    conv3x3_v3<false, false, false><<<gm, blk, 0, stream>>>(t1,  wb2, fb2, nullptr, fp);
    // multiplicative path (fused * fp -> feat f32 NCHW)
    conv3x3_v3<true,  false, false><<<gm, blk, 0, stream>>>(kfb, wb3, mb1, nullptr, t1);
    conv3x3_v3<false, true,  true ><<<gm, blk, 0, stream>>>(t1,  wb4, mb2, fp,      feat);

    // local filter path (fused pair)
    lp_fused_k<<<gp, blk, 0, stream>>>(kfb, wl1, lb1, wl2, lb2, lpb);

    // dynamic local conv + residual
    local_conv_v2<<<glc, blk, 0, stream>>>(x, feat, lpb, out);
}

// Round 6
// 194.069 us; speedup vs baseline: 11.0189x; 1.0797x over previous
//
#include <hip/hip_runtime.h>
#include <hip/hip_bf16.h>

#define Cc 64
#define Hc 128
#define Wc 128
#define HWc (Hc * Wc)
#define Bc 4

typedef __attribute__((ext_vector_type(8))) short short8;
typedef __attribute__((ext_vector_type(4))) float float4v;

static __device__ __forceinline__ unsigned short f2bu(float f) {
    __hip_bfloat16 h = __float2bfloat16(f);
    return *(unsigned short*)&h;
}

// ---------------------------------------------------------------------------
// Merged NCHW f32 -> NHWC bf16 for x (fused ReLU) and kf. grid = 512.
// ---------------------------------------------------------------------------
__global__ __launch_bounds__(256) void cvt_both_k(
    const float* __restrict__ x, const float* __restrict__ kf,
    unsigned short* __restrict__ xb, unsigned short* __restrict__ kfb)
{
    const int bid = blockIdx.x;
    const bool isx = bid < 256;
    const float* src = isx ? x : kf;
    unsigned short* dst = isx ? xb : kfb;
    const int px = (isx ? bid : bid - 256) * 256 + threadIdx.x;
    const int b  = px >> 14;
    const int hw = px & 16383;
    const float* s = src + (size_t)b * Cc * HWc + hw;
    unsigned short* d = dst + (size_t)px * Cc;

#pragma unroll
    for (int c8 = 0; c8 < 8; ++c8) {
        unsigned int pk[4];
#pragma unroll
        for (int jp = 0; jp < 4; ++jp) {
            float v0 = s[(size_t)(c8 * 8 + jp * 2 + 0) * HWc];
            float v1 = s[(size_t)(c8 * 8 + jp * 2 + 1) * HWc];
            if (isx) { v0 = fmaxf(v0, 0.f); v1 = fmaxf(v1, 0.f); }
            pk[jp] = (unsigned int)f2bu(v0) | ((unsigned int)f2bu(v1) << 16);
        }
        *(uint4*)(d + c8 * 8) = make_uint4(pk[0], pk[1], pk[2], pk[3]);
    }
}

// ---------------------------------------------------------------------------
// All weight packing in one launch (as round 5).
// ---------------------------------------------------------------------------
__global__ __launch_bounds__(256) void wpack_all_k(
    const float* __restrict__ fw1, const float* __restrict__ fw2,
    const float* __restrict__ mw1, const float* __restrict__ mw2,
    const float* __restrict__ lw1, const float* __restrict__ lw2,
    unsigned short* __restrict__ wbase)
{
    const int bid = blockIdx.x;
    const int tid = threadIdx.x;
    if (bid < 72) {
        const int which = bid / 18;
        const float* w = (which == 0) ? fw1 : (which == 1) ? fw2 : (which == 2) ? mw1 : mw2;
        unsigned short* wb = wbase + (size_t)which * 36864;
        const int g = (bid % 18) * 256 + tid;
        if (g >= 4608) return;
        const int lane = g & 63;
        const int smt  = g >> 6;
        const int s    = smt >> 2;
        const int mt   = smt & 3;
        const int co   = mt * 16 + (lane & 15);
        const int kb   = s * 32 + (lane >> 4) * 8;
        unsigned int pk[4];
#pragma unroll
        for (int jp = 0; jp < 4; ++jp) {
            int k0 = kb + jp * 2, k1 = k0 + 1;
            float v0 = w[((size_t)co * Cc + (k0 & 63)) * 9 + (k0 >> 6)];
            float v1 = w[((size_t)co * Cc + (k1 & 63)) * 9 + (k1 >> 6)];
            pk[jp] = (unsigned int)f2bu(v0) | ((unsigned int)f2bu(v1) << 16);
        }
        *(uint4*)(wb + (size_t)g * 8) = make_uint4(pk[0], pk[1], pk[2], pk[3]);
    } else {
        const int which = (bid - 72) >> 1;
        const float* w = which ? lw2 : lw1;
        const int Cout = which ? 49 : 64;
        unsigned short* wb = wbase + 4 * 36864 + (size_t)which * 4096;
        const int g = ((bid - 72) & 1) * 256 + tid;
        const int lane = g & 63;
        const int smt  = g >> 6;
        const int s    = smt >> 2;
        const int mt   = smt & 3;
        const int co   = mt * 16 + (lane & 15);
        const int kb   = s * 32 + (lane >> 4) * 8;
        unsigned int pk[4];
#pragma unroll
        for (int jp = 0; jp < 4; ++jp) {
            int k0 = kb + jp * 2, k1 = k0 + 1;
            float v0 = (co < Cout) ? w[(size_t)co * Cc + k0] : 0.f;
            float v1 = (co < Cout) ? w[(size_t)co * Cc + k1] : 0.f;
            pk[jp] = (unsigned int)f2bu(v0) | ((unsigned int)f2bu(v1) << 16);
        }
        *(uint4*)(wb + (size_t)g * 8) = make_uint4(pk[0], pk[1], pk[2], pk[3]);
    }
}

// ---------------------------------------------------------------------------
// conv3x3 v4: as v3 (2 rows x 64 px x 64 co per block, 2x2 wave split) but
// with an explicitly software-pipelined k-loop: A-frags (global) and B-frags
// (LDS) for step s+1 are loaded into a register double-buffer before the
// MFMAs of step s. DUAL variant packs two independent convs in one dispatch
// (grid.z = 2*B, identical epilogue config).
// ---------------------------------------------------------------------------
template <bool RELU_OUT, bool MUL, bool F32_NCHW_OUT, bool DUAL>
__global__ __launch_bounds__(256) void conv3x3_v4(
    const unsigned short* __restrict__ in0,
    const unsigned short* __restrict__ in1,
    const unsigned short* __restrict__ wfrag0,
    const unsigned short* __restrict__ wfrag1,
    const float* __restrict__ bias0,
    const float* __restrict__ bias1,
    const unsigned short* __restrict__ fp_mul,
    void* __restrict__ out0, void* __restrict__ out1)
{
    __shared__ unsigned short s_b[264 * 64];   // 33792 B

    const int tid  = threadIdx.x;
    const int lane = tid & 63;
    const int wv   = tid >> 6;
    const int w0   = blockIdx.x * 64;
    const int h0   = blockIdx.y * 2;
    const int zz   = blockIdx.z;
    const int b    = DUAL ? (zz & 3) : zz;
    const bool sel = DUAL ? (zz >> 2) : 0;

    const unsigned short* in    = sel ? in1 : in0;
    const unsigned short* wfrag = sel ? wfrag1 : wfrag0;
    const float*          bias  = sel ? bias1 : bias0;
    void*                 out   = sel ? out1 : out0;

    // ---- stage 4 rows (h0-1..h0+2) x 66 cols x 64 ch ----
    for (int u = tid; u < 264; u += 256) {
        const int r  = u / 66;
        const int c  = u - r * 66;
        const int gh = h0 - 1 + r;
        const int gw = w0 - 1 + c;
        const bool ok = ((unsigned)gh < (unsigned)Hc) && ((unsigned)gw < (unsigned)Wc);
        const unsigned short* src =
            in + (((size_t)b * Hc + (ok ? gh : 0)) * Wc + (ok ? gw : 0)) * Cc;
        const int sw = u & 7;
#pragma unroll
        for (int ch = 0; ch < 8; ++ch) {
            uint4 v = ok ? *(const uint4*)(src + ch * 8) : make_uint4(0, 0, 0, 0);
            *(uint4*)&s_b[u * 64 + ((ch ^ sw) << 3)] = v;
        }
    }
    __syncthreads();

    const int rowsel = wv >> 1;
    const int cohalf = wv & 1;
    const int quad   = lane >> 4;
    const int n15    = lane & 15;

    // A(s,m) at wfrag[((s*4 + cohalf*2 + m)*64 + lane)*8]
    const unsigned short* aptr = wfrag + (((size_t)(cohalf * 2) * 64 + lane) << 3);

    int rowb[3];
#pragma unroll
    for (int ky = 0; ky < 3; ++ky) rowb[ky] = (rowsel + ky) * 66 + n15;

    float4v acc[2][4];
#pragma unroll
    for (int m = 0; m < 2; ++m)
#pragma unroll
        for (int nt = 0; nt < 4; ++nt) acc[m][nt] = (float4v){0.f, 0.f, 0.f, 0.f};

#define LOAD_A(s, m) (*(const short8*)(aptr + (size_t)(s) * 2048 + (size_t)(m) * 512))
#define LOAD_B(s, nt) ({                                                     \
        const int tap_ = (s) >> 1;                                           \
        const int qb_  = rowb[tap_ / 3] + tap_ % 3;                          \
        const int ch0_ = ((s) & 1) * 4 + quad;                               \
        *(const short8*)&s_b[(qb_ + (nt) * 16) * 64 + ((ch0_ ^ (qb_ & 7)) << 3)]; })

    short8 a_cur[2], b_cur[4];
#pragma unroll
    for (int m = 0; m < 2; ++m) a_cur[m] = LOAD_A(0, m);
#pragma unroll
    for (int nt = 0; nt < 4; ++nt) b_cur[nt] = LOAD_B(0, nt);

#pragma unroll
    for (int s = 0; s < 18; ++s) {
        short8 a_nxt[2], b_nxt[4];
        if (s < 17) {
#pragma unroll
            for (int m = 0; m < 2; ++m) a_nxt[m] = LOAD_A(s + 1, m);
#pragma unroll
            for (int nt = 0; nt < 4; ++nt) b_nxt[nt] = LOAD_B(s + 1, nt);
        }
#pragma unroll
        for (int nt = 0; nt < 4; ++nt)
#pragma unroll
            for (int m = 0; m < 2; ++m)
                acc[m][nt] = __builtin_amdgcn_mfma_f32_16x16x32_bf16(
                    a_cur[m], b_cur[nt], acc[m][nt], 0, 0, 0);
        if (s < 17) {
#pragma unroll
            for (int m = 0; m < 2; ++m) a_cur[m] = a_nxt[m];
#pragma unroll
            for (int nt = 0; nt < 4; ++nt) b_cur[nt] = b_nxt[nt];
        }
    }
#undef LOAD_A
#undef LOAD_B

    // ---- epilogue ----
    const int h = h0 + rowsel;
#pragma unroll
    for (int m = 0; m < 2; ++m) {
        const int mt  = cohalf * 2 + m;
        const int co0 = mt * 16 + quad * 4;
        float4 bv = *(const float4*)&bias[co0];
#pragma unroll
        for (int nt = 0; nt < 4; ++nt) {
            const size_t pix = ((size_t)b * Hc + h) * Wc + w0 + nt * 16 + n15;
            float v[4] = {acc[m][nt][0] + bv.x, acc[m][nt][1] + bv.y,
                          acc[m][nt][2] + bv.z, acc[m][nt][3] + bv.w};
            if (RELU_OUT)
#pragma unroll
                for (int r = 0; r < 4; ++r) v[r] = fmaxf(v[r], 0.f);
            if (MUL) {
                uint2 mm = *(const uint2*)&fp_mul[pix * Cc + co0];
                v[0] *= __uint_as_float((mm.x & 0xffffu) << 16);
                v[1] *= __uint_as_float(mm.x & 0xffff0000u);
                v[2] *= __uint_as_float((mm.y & 0xffffu) << 16);
                v[3] *= __uint_as_float(mm.y & 0xffff0000u);
            }
            if (F32_NCHW_OUT) {
                float* op = (float*)out;
#pragma unroll
                for (int r = 0; r < 4; ++r)
                    op[((size_t)b * Cc + co0 + r) * HWc + (size_t)h * Wc + w0 + nt * 16 + n15] = v[r];
            } else {
                unsigned short* op = (unsigned short*)out;
                ushort4 pk;
                pk.x = f2bu(v[0]); pk.y = f2bu(v[1]); pk.z = f2bu(v[2]); pk.w = f2bu(v[3]);
                *(ushort4*)&op[pix * Cc + co0] = pk;
            }
        }
    }
}

// ---------------------------------------------------------------------------
// Fused local-filter path (as round 5).
// ---------------------------------------------------------------------------
__global__ __launch_bounds__(256) void lp_fused_k(
    const unsigned short* __restrict__ in,
    const unsigned short* __restrict__ w1,
    const float* __restrict__ b1,
    const unsigned short* __restrict__ w2,
    const float* __restrict__ b2,
    float* __restrict__ out)
{
    __shared__ unsigned short s_t[4 * 1024];

    const int tid  = threadIdx.x;
    const int lane = tid & 63;
    const int wv   = tid >> 6;
    const int quad = lane >> 4;
    const int p    = lane & 15;
    const size_t pix = (size_t)blockIdx.x * 64 + wv * 16 + p;
    unsigned short* st = &s_t[wv * 1024];

    float4v acc1[4];
#pragma unroll
    for (int mt = 0; mt < 4; ++mt) acc1[mt] = (float4v){0.f, 0.f, 0.f, 0.f};
#pragma unroll
    for (int s = 0; s < 2; ++s) {
        short8 bfr = *(const short8*)&in[pix * Cc + s * 32 + quad * 8];
#pragma unroll
        for (int mt = 0; mt < 4; ++mt) {
            short8 afr = *(const short8*)&w1[(size_t)(((s * 4 + mt) << 6) + lane) << 3];
            acc1[mt] = __builtin_amdgcn_mfma_f32_16x16x32_bf16(afr, bfr, acc1[mt], 0, 0, 0);
        }
    }

#pragma unroll
    for (int mt = 0; mt < 4; ++mt) {
        const int co0 = mt * 16 + quad * 4;
        float4 bv = *(const float4*)&b1[co0];
        ushort4 pk;
        pk.x = f2bu(fmaxf(acc1[mt][0] + bv.x, 0.f));
        pk.y = f2bu(fmaxf(acc1[mt][1] + bv.y, 0.f));
        pk.z = f2bu(fmaxf(acc1[mt][2] + bv.z, 0.f));
        pk.w = f2bu(fmaxf(acc1[mt][3] + bv.w, 0.f));
        const int cg = co0 >> 3;
        *(ushort4*)&st[p * 64 + ((cg ^ (p & 7)) << 3) + (quad & 1) * 4] = pk;
    }
    __syncthreads();

    float4v acc2[4];
#pragma unroll
    for (int mt = 0; mt < 4; ++mt) acc2[mt] = (float4v){0.f, 0.f, 0.f, 0.f};
#pragma unroll
    for (int s = 0; s < 2; ++s) {
        const int cg = s * 4 + quad;
        short8 bfr = *(const short8*)&st[p * 64 + ((cg ^ (p & 7)) << 3)];
#pragma unroll
        for (int mt = 0; mt < 4; ++mt) {
            short8 afr = *(const short8*)&w2[(size_t)(((s * 4 + mt) << 6) + lane) << 3];
            acc2[mt] = __builtin_amdgcn_mfma_f32_16x16x32_bf16(afr, bfr, acc2[mt], 0, 0, 0);
        }
    }

    float v[4][4];
    float partial = 0.f;
#pragma unroll
    for (int mt = 0; mt < 4; ++mt) {
#pragma unroll
        for (int r = 0; r < 4; ++r) {
            const int tap = mt * 16 + quad * 4 + r;
            float val = (tap < 49) ? (acc2[mt][r] + b2[tap]) : 0.f;
            v[mt][r] = val;
            partial += val;
        }
    }
    partial += __shfl_xor(partial, 16, 64);
    partial += __shfl_xor(partial, 32, 64);
    const float m = partial * (1.f / 49.f) - (1.f / 49.f);

    const int b  = (int)(pix >> 14);
    const int hw = (int)(pix & 16383);
#pragma unroll
    for (int mt = 0; mt < 4; ++mt) {
#pragma unroll
        for (int r = 0; r < 4; ++r) {
            const int tap = mt * 16 + quad * 4 + r;
            if (tap < 49)
                out[((size_t)b * 49 + tap) * HWc + hw] = v[mt][r] - m;
        }
    }
}

// ---------------------------------------------------------------------------
// Dynamic local 7x7 conv + residual (as round 5).
// ---------------------------------------------------------------------------
__global__ __launch_bounds__(256) void local_conv_v2(
    const float* __restrict__ x, const float* __restrict__ feat,
    const float* __restrict__ lp, float* __restrict__ out)
{
    const int tid = threadIdx.x;
    const int w4  = (tid & 31) * 4;
    const int ro  = tid >> 5;
    const int h   = blockIdx.x * 8 + ro;
    const int c0  = blockIdx.y * 4;
    const int b   = blockIdx.z;

    float msk[12];
#pragma unroll
    for (int e = 0; e < 12; ++e) {
        int gw = w4 - 4 + e;
        msk[e] = ((unsigned)gw < (unsigned)Wc) ? 1.f : 0.f;
    }

    float acc[4][4];
#pragma unroll
    for (int ch = 0; ch < 4; ++ch)
#pragma unroll
        for (int p = 0; p < 4; ++p) acc[ch][p] = 0.f;

    const float* lpb = lp + (size_t)b * 49 * HWc + (size_t)h * Wc + w4;
    const float* fb  = feat + ((size_t)b * Cc + c0) * HWc;

#pragma unroll
    for (int dy = 0; dy < 7; ++dy) {
        const int gh = h + dy - 3;
        if ((unsigned)gh >= (unsigned)Hc) continue;

        float4 lp4[7];
#pragma unroll
        for (int dx = 0; dx < 7; ++dx)
            lp4[dx] = *(const float4*)&lpb[(size_t)(dy * 7 + dx) * HWc];

        const float* frow = fb + (size_t)gh * Wc + w4;
#pragma unroll
        for (int ch = 0; ch < 4; ++ch) {
            const float* fr = frow + (size_t)ch * HWc;
            float4 a  = *(const float4*)(fr - 4);
            float4 bq = *(const float4*)(fr);
            float4 cq = *(const float4*)(fr + 4);
            float f[12];
            f[0]  = a.x;            f[1]  = a.y * msk[1];
            f[2]  = a.z * msk[2];   f[3]  = a.w * msk[3];
            f[4]  = bq.x;           f[5]  = bq.y;
            f[6]  = bq.z;           f[7]  = bq.w;
            f[8]  = cq.x * msk[8];  f[9]  = cq.y * msk[9];
            f[10] = cq.z * msk[10]; f[11] = cq.w;
#pragma unroll
            for (int dx = 0; dx < 7; ++dx) {
                const float* lpv = (const float*)&lp4[dx];
#pragma unroll
                for (int p = 0; p < 4; ++p)
                    acc[ch][p] = fmaf(f[p + dx + 1], lpv[p], acc[ch][p]);
            }
        }
    }

#pragma unroll
    for (int ch = 0; ch < 4; ++ch) {
        const size_t idx = ((size_t)b * Cc + c0 + ch) * HWc + (size_t)h * Wc + w4;
        float4 xv = *(const float4*)&x[idx];
        float4 r  = {acc[ch][0] + xv.x, acc[ch][1] + xv.y,
                     acc[ch][2] + xv.z, acc[ch][3] + xv.w};
        *(float4*)&out[idx] = r;
    }
}

// ---------------------------------------------------------------------------
extern "C" void kernel_launch(void* const* d_in, const int* in_sizes, int n_in,
                              void* d_out, int out_size, void* d_ws, size_t ws_size,
                              hipStream_t stream)
{
    const float* x   = (const float*)d_in[0];
    const float* kf  = (const float*)d_in[1];
    const float* fw1 = (const float*)d_in[2];
    const float* fb1 = (const float*)d_in[3];
    const float* fw2 = (const float*)d_in[4];
    const float* fb2 = (const float*)d_in[5];
    const float* mw1 = (const float*)d_in[6];
    const float* mb1 = (const float*)d_in[7];
    const float* mw2 = (const float*)d_in[8];
    const float* mb2 = (const float*)d_in[9];
    const float* lw1 = (const float*)d_in[10];
    const float* lb1 = (const float*)d_in[11];
    const float* lw2 = (const float*)d_in[12];
    const float* lb2 = (const float*)d_in[13];

    float* out = (float*)d_out;
    char*  ws  = (char*)d_ws;

    const size_t NBH = (size_t)Bc * HWc * Cc * 2;   // bf16 NHWC: 8.4 MB
    const size_t NBF = (size_t)Bc * Cc * HWc * 4;   // f32 NCHW: 16.8 MB
    const size_t LPB = (size_t)Bc * 49 * HWc * 4;   // 12.8 MB

    unsigned short* t1f   = (unsigned short*)(ws);
    unsigned short* t1m   = (unsigned short*)(ws + NBH);
    float*          feat  = (float*)(ws + 2 * NBH);
    float*          lpb   = (float*)(ws + 2 * NBH + NBF);
    unsigned short* xb    = (unsigned short*)(ws + 2 * NBH + NBF + LPB);
    unsigned short* kfb   = (unsigned short*)((char*)xb + NBH);
    unsigned short* wbase = (unsigned short*)((char*)kfb + NBH);
    unsigned short* wb1   = wbase;
    unsigned short* wb2   = wbase + 36864;
    unsigned short* wb3   = wbase + 2 * 36864;
    unsigned short* wb4   = wbase + 3 * 36864;
    unsigned short* wl1   = wbase + 4 * 36864;
    unsigned short* wl2   = wbase + 4 * 36864 + 4096;
    unsigned short* fp    = (unsigned short*)d_out;   // park fp in d_out

    dim3 blk(256);
    dim3 gm (Wc / 64, Hc / 2, Bc);
    dim3 gm2(Wc / 64, Hc / 2, Bc * 2);
    dim3 gp (Bc * HWc / 64);
    dim3 glc(Hc / 8, Cc / 4, Bc);

    cvt_both_k<<<dim3(512), blk, 0, stream>>>(x, kf, xb, kfb);
    wpack_all_k<<<dim3(76), blk, 0, stream>>>(fw1, fw2, mw1, mw2, lw1, lw2, wbase);

    // conv1 of both paths in one dual dispatch (both: relu-out, bf16 NHWC out)
    conv3x3_v4<true, false, false, true><<<gm2, blk, 0, stream>>>(
        xb, kfb, wb1, wb3, fb1, mb1, nullptr, t1f, t1m);

    // feature conv2 -> fp (bf16, parked in d_out)
    conv3x3_v4<false, false, false, false><<<gm, blk, 0, stream>>>(
        t1f, nullptr, wb2, nullptr, fb2, nullptr, nullptr, fp, nullptr);

    // mult conv2, fused * fp -> feat (f32 NCHW)
    conv3x3_v4<false, true, true, false><<<gm, blk, 0, stream>>>(
        t1m, nullptr, wb4, nullptr, mb2, nullptr, fp, feat, nullptr);

    // local filter path (fused pair)
    lp_fused_k<<<gp, blk, 0, stream>>>(kfb, wl1, lb1, wl2, lb2, lpb);

    // dynamic local conv + residual
    local_conv_v2<<<glc, blk, 0, stream>>>(x, feat, lpb, out);
}